// Round 3
// baseline (594.793 us; speedup 1.0000x reference)
//
#include <hip/hip_runtime.h>
#include <math.h>

#define BATCH 2
#define NCH 21
#define CPAD 24            // channels padded to 24 (48 B fp16 per pixel)
#define HH 512
#define WW 512
#define KS 5
#define RAD 2
#define NTAPS 25
#define NUM_ITERS 10

// weights-kernel tile geometry
#define TXW 32
#define TYW 8
#define HXW (TXW + 2*RAD)   // 36
#define HYW (TYW + 2*RAD)   // 12
#define HPXW (HXW * HYW)    // 432

// fused-pair kernel geometry: 32x32 inner tile, 512 threads, 2 y-stacked px/thread
#define TW 32
#define TH 32
#define NTHRP 512
#define SX 40               // staged tile (4-px halo for 2 iters)
#define SY 40
#define SPX (SX * SY)       // 1600
#define SCHUNK (SPX * 3)    // 4800 16-byte DMA chunks
#define SHBYTES (SPX * CPAD * 2)   // 76800 B dynamic LDS
#define EX 36               // extended (iter-1 output) region
#define EY 36
#define EPX (EX * EY)       // 1296
#define RINGP 136           // ring y-pairs covering the 272 ring pixels

typedef _Float16 f16;
typedef _Float16 half8 __attribute__((ext_vector_type(8)));
typedef _Float16 half2v __attribute__((ext_vector_type(2)));

__device__ __forceinline__ int refl(int i, int n) {
    if (i < 0) i = -i;
    if (i >= n) i = 2*n - 2 - i;
    return i;
}

// weight-element selector (t is a compile-time constant after unrolling)
#define WSEL(h0, h1, h2, hl, t) \
    ((t) < 8 ? (h0)[(t)] : (t) < 16 ? (h1)[(t) - 8] : (t) < 24 ? (h2)[(t) - 16] : (hl))

// ---------------- Kernel A: combined normalized weights (unchanged) ----------------
__global__ __launch_bounds__(256) void weights_kernel(const float* __restrict__ image,
                                                      const float* __restrict__ edges,
                                                      f16* __restrict__ wcA,
                                                      f16* __restrict__ wcB16) {
    __shared__ float sr_[HYW][HXW];
    __shared__ float sg_[HYW][HXW];
    __shared__ float sb_[HYW][HXW];
    __shared__ float se_[HYW][HXW];

    const int tx = threadIdx.x;
    const int ty = threadIdx.y;
    const int tid = ty * TXW + tx;
    const int x0 = blockIdx.x * TXW;
    const int y0 = blockIdx.y * TYW;
    const int b = blockIdx.z;
    const int x = x0 + tx;
    const int y = y0 + ty;
    const size_t plane = (size_t)HH * WW;
    const float* img = image + (size_t)b * 3 * plane;
    const float* edg = edges + (size_t)b * plane;

    for (int i = tid; i < HPXW; i += TXW * TYW) {
        int ly = i / HXW, lx = i - ly * HXW;
        int gy = refl(y0 + ly - RAD, HH);
        int gx = refl(x0 + lx - RAD, WW);
        int g = gy * WW + gx;
        sr_[ly][lx] = img[g];
        sg_[ly][lx] = img[plane + g];
        sb_[ly][lx] = img[2 * plane + g];
        se_[ly][lx] = edg[g];
    }
    __syncthreads();

    float gs[3];
    gs[0] = 1.0f; gs[1] = __expf(-1.0f / 50.0f); gs[2] = __expf(-4.0f / 50.0f);
    float gb[3];
    gb[0] = 1.0f; gb[1] = __expf(-2.0f); gb[2] = __expf(-8.0f);
    float gbs = gb[0] + 2.0f * (gb[1] + gb[2]);
    gb[0] /= gbs; gb[1] /= gbs; gb[2] /= gbs;

    const float r0 = sr_[ty + RAD][tx + RAD];
    const float g0 = sg_[ty + RAD][tx + RAD];
    const float b0 = sb_[ty + RAD][tx + RAD];
    const float e0 = se_[ty + RAD][tx + RAD];

    float wr[NTAPS], we[NTAPS];
    float sr = 0.f, se = 0.f;
#pragma unroll
    for (int dy = 0; dy < KS; dy++) {
#pragma unroll
        for (int dx = 0; dx < KS; dx++) {
            float sp = gs[abs(dy - RAD)] * gs[abs(dx - RAD)];
            float d = fabsf(sr_[ty + dy][tx + dx] - r0)
                    + fabsf(sg_[ty + dy][tx + dx] - g0)
                    + fabsf(sb_[ty + dy][tx + dx] - b0);
            float w1 = sp * __expf(-2.0f * d * d);
            float de = fabsf(se_[ty + dy][tx + dx] - e0);
            float w2 = sp * __expf(-2.0f * de * de);
            wr[dy * KS + dx] = w1;
            we[dy * KS + dx] = w2;
            sr += w1;
            se += w2;
        }
    }
    float isr = 1.0f / sr, ise = 1.0f / se;
    float wt[NTAPS];
#pragma unroll
    for (int t = 0; t < NTAPS; t++) {
        int dy = t / KS, dx = t % KS;
        float g2 = gb[abs(dy - RAD)] * gb[abs(dx - RAD)];
        wt[t] = g2 + wr[t] * isr + we[t] * ise;
    }
    const size_t pixoff = (size_t)b * plane + (size_t)y * WW + x;
    half8* wo = (half8*)(wcA + pixoff * 24);
#pragma unroll
    for (int g = 0; g < 3; g++) {
        half8 v;
#pragma unroll
        for (int k = 0; k < 8; k++) v[k] = (f16)wt[g * 8 + k];
        wo[g] = v;
    }
    wcB16[pixoff] = (f16)wt[24];
}

// ---------------- Kernel B: initial softmax -> interleaved fp16 q + fp16 unary (unchanged) ----------------
__global__ void init_kernel(const float* __restrict__ unary,
                            f16* __restrict__ q,
                            f16* __restrict__ u16) {
    int idx = blockIdx.x * blockDim.x + threadIdx.x;
    if (idx >= BATCH * HH * WW) return;
    int p = idx % (HH * WW);
    int b = idx / (HH * WW);
    const size_t plane = (size_t)HH * WW;
    const float* u = unary + (size_t)b * NCH * plane + p;
    float l[CPAD];
    float m = -1e30f;
#pragma unroll
    for (int c = 0; c < NCH; c++) { l[c] = u[c * plane]; m = fmaxf(m, l[c]); }
    l[21] = 0.f; l[22] = 0.f; l[23] = 0.f;

    half8* uo = (half8*)(u16 + ((size_t)b * plane + p) * CPAD);
#pragma unroll
    for (int g = 0; g < 3; g++) {
        half8 v;
#pragma unroll
        for (int k = 0; k < 8; k++) v[k] = (f16)l[g * 8 + k];
        uo[g] = v;
    }

    float s = 0.f;
    float e[CPAD];
#pragma unroll
    for (int c = 0; c < NCH; c++) { e[c] = __expf(l[c] - m); s += e[c]; }
    float is = 1.0f / s;
    e[21] = 0.f; e[22] = 0.f; e[23] = 0.f;
    half8* qo = (half8*)(q + ((size_t)b * plane + p) * CPAD);
#pragma unroll
    for (int g = 0; g < 3; g++) {
        half8 v;
#pragma unroll
        for (int k = 0; k < 8; k++) v[k] = (f16)(e[g * 8 + k] * is);
        qo[g] = v;
    }
}

// 11 packed MACs (21 channels + 1 pad) for one pixel from one tap position
#define PK11(acc2, wv_, v0, v1, v2) do {                                                            \
    acc2[0]  = __builtin_elementwise_fma(wv_, __builtin_shufflevector(v0, v0, 0, 1), acc2[0]);      \
    acc2[1]  = __builtin_elementwise_fma(wv_, __builtin_shufflevector(v0, v0, 2, 3), acc2[1]);      \
    acc2[2]  = __builtin_elementwise_fma(wv_, __builtin_shufflevector(v0, v0, 4, 5), acc2[2]);      \
    acc2[3]  = __builtin_elementwise_fma(wv_, __builtin_shufflevector(v0, v0, 6, 7), acc2[3]);      \
    acc2[4]  = __builtin_elementwise_fma(wv_, __builtin_shufflevector(v1, v1, 0, 1), acc2[4]);      \
    acc2[5]  = __builtin_elementwise_fma(wv_, __builtin_shufflevector(v1, v1, 2, 3), acc2[5]);      \
    acc2[6]  = __builtin_elementwise_fma(wv_, __builtin_shufflevector(v1, v1, 4, 5), acc2[6]);      \
    acc2[7]  = __builtin_elementwise_fma(wv_, __builtin_shufflevector(v1, v1, 6, 7), acc2[7]);      \
    acc2[8]  = __builtin_elementwise_fma(wv_, __builtin_shufflevector(v2, v2, 0, 1), acc2[8]);      \
    acc2[9]  = __builtin_elementwise_fma(wv_, __builtin_shufflevector(v2, v2, 2, 3), acc2[9]);      \
    acc2[10] = __builtin_elementwise_fma(wv_, __builtin_shufflevector(v2, v2, 4, 5), acc2[10]);     \
} while (0)

// paired conv over a y-stacked pixel pair: 6 rows x 5 cols, each 48B tap read shared by
// both pixels (rows 1..4); pixel A uses row index r, pixel B uses r-1.
// per-pixel accumulation order is identical to the unpaired version (dy outer, dx inner).
#define CONV_PAIR_STAGED(accA, accB, lds, row0, col0, stride,                                       \
                         WA0, WA1, WA2, WAL, WB0, WB1, WB2, WBL)                                    \
    {                                                                                               \
        _Pragma("unroll")                                                                           \
        for (int r_ = 0; r_ < 6; r_++) {                                                            \
            _Pragma("unroll")                                                                       \
            for (int dx_ = 0; dx_ < 5; dx_++) {                                                     \
                const f16* tp_ = (lds) + ((size_t)((row0) + r_) * (stride) + (col0) + dx_) * CPAD;  \
                half8 v0_ = *(const half8*)(tp_);                                                   \
                half8 v1_ = *(const half8*)(tp_ + 8);                                               \
                half8 v2_ = *(const half8*)(tp_ + 16);                                              \
                if (r_ < 5) {                                                                       \
                    const f16 wA_ = WSEL(WA0, WA1, WA2, WAL, r_ * 5 + dx_);                         \
                    const half2v wvA_ = {wA_, wA_};                                                 \
                    PK11(accA, wvA_, v0_, v1_, v2_);                                                \
                }                                                                                   \
                if (r_ >= 1) {                                                                      \
                    const f16 wB_ = WSEL(WB0, WB1, WB2, WBL, (r_ - 1) * 5 + dx_);                   \
                    const half2v wvB_ = {wB_, wB_};                                                 \
                    PK11(accB, wvB_, v0_, v1_, v2_);                                                \
                }                                                                                   \
            }                                                                                       \
        }                                                                                           \
    }

// same but with per-row / per-col index arrays (reflected indexing for iteration 2)
#define CONV_PAIR_IDX(accA, accB, lds, ryArr, rxArr, stride,                                        \
                      WA0, WA1, WA2, WAL, WB0, WB1, WB2, WBL)                                       \
    {                                                                                               \
        _Pragma("unroll")                                                                           \
        for (int r_ = 0; r_ < 6; r_++) {                                                            \
            _Pragma("unroll")                                                                       \
            for (int dx_ = 0; dx_ < 5; dx_++) {                                                     \
                const f16* tp_ = (lds) + ((size_t)(ryArr)[r_] * (stride) + (rxArr)[dx_]) * CPAD;    \
                half8 v0_ = *(const half8*)(tp_);                                                   \
                half8 v1_ = *(const half8*)(tp_ + 8);                                               \
                half8 v2_ = *(const half8*)(tp_ + 16);                                              \
                if (r_ < 5) {                                                                       \
                    const f16 wA_ = WSEL(WA0, WA1, WA2, WAL, r_ * 5 + dx_);                         \
                    const half2v wvA_ = {wA_, wA_};                                                 \
                    PK11(accA, wvA_, v0_, v1_, v2_);                                                \
                }                                                                                   \
                if (r_ >= 1) {                                                                      \
                    const f16 wB_ = WSEL(WB0, WB1, WB2, WBL, (r_ - 1) * 5 + dx_);                   \
                    const half2v wvB_ = {wB_, wB_};                                                 \
                    PK11(accB, wvB_, v0_, v1_, v2_);                                                \
                }                                                                                   \
            }                                                                                       \
        }                                                                                           \
    }

// logits: l[c] = u[c] - acc2 (promote f16 acc to f32 here)
#define LOGITS_FROM_PK(l, acc2, U0, U1, U2)                                            \
    {                                                                                  \
        _Pragma("unroll")                                                              \
        for (int j = 0; j < 10; j++) {                                                 \
            l[2 * j]     = -(float)acc2[j][0];                                         \
            l[2 * j + 1] = -(float)acc2[j][1];                                         \
        }                                                                              \
        l[20] = -(float)acc2[10][0];                                                   \
        _Pragma("unroll")                                                              \
        for (int k = 0; k < 8; k++) l[k] += (float)U0[k];                              \
        _Pragma("unroll")                                                              \
        for (int k = 0; k < 8; k++) l[8 + k] += (float)U1[k];                          \
        _Pragma("unroll")                                                              \
        for (int k = 0; k < 5; k++) l[16 + k] += (float)U2[k];                         \
    }

// logits -> softmax -> packed f16 q' triple (fully inline; no address-taken temps
// crossing a call boundary)
#define FINISH_PX(acc2, U0, U1, U2, o0, o1, o2)                                        \
    {                                                                                  \
        float l_[NCH];                                                                 \
        LOGITS_FROM_PK(l_, acc2, U0, U1, U2);                                          \
        float m_ = l_[0];                                                              \
        _Pragma("unroll")                                                              \
        for (int c = 1; c < NCH; c++) m_ = fmaxf(m_, l_[c]);                           \
        float s_ = 0.f;                                                                \
        _Pragma("unroll")                                                              \
        for (int c = 0; c < NCH; c++) { l_[c] = __expf(l_[c] - m_); s_ += l_[c]; }     \
        float is_ = 1.0f / s_;                                                         \
        _Pragma("unroll")                                                              \
        for (int k = 0; k < 8; k++) (o0)[k] = (f16)(l_[k] * is_);                      \
        _Pragma("unroll")                                                              \
        for (int k = 0; k < 8; k++) (o1)[k] = (f16)(l_[8 + k] * is_);                  \
        _Pragma("unroll")                                                              \
        for (int k = 0; k < 5; k++) (o2)[k] = (f16)(l_[16 + k] * is_);                 \
        (o2)[5] = (f16)0.f; (o2)[6] = (f16)0.f; (o2)[7] = (f16)0.f;                    \
    }

// logits -> softmax -> strided fp32 store (final iteration)
#define FINISH_PX_F32(acc2, U0, U1, U2, qo, plane)                                     \
    {                                                                                  \
        float l_[NCH];                                                                 \
        LOGITS_FROM_PK(l_, acc2, U0, U1, U2);                                          \
        float m_ = l_[0];                                                              \
        _Pragma("unroll")                                                              \
        for (int c = 1; c < NCH; c++) m_ = fmaxf(m_, l_[c]);                           \
        float s_ = 0.f;                                                                \
        _Pragma("unroll")                                                              \
        for (int c = 0; c < NCH; c++) { l_[c] = __expf(l_[c] - m_); s_ += l_[c]; }     \
        float is_ = 1.0f / s_;                                                         \
        _Pragma("unroll")                                                              \
        for (int c = 0; c < NCH; c++) (qo)[c * (plane)] = l_[c] * is_;                 \
    }

// ---------------- Kernel C: TWO fused CRF iterations, 32x32 tile, 2 y-stacked px/thread ----
// 512 threads (8 waves), 76.8 KB dynamic LDS -> 2 blocks/CU = 16 waves/CU, grid 512 = all
// blocks co-resident (no tail generation). __launch_bounds__(512,4) caps VGPR at 128, the
// requirement for 2-block residency (round-1 showed 128 is the natural allocation).
template <bool FINAL>
__global__ __launch_bounds__(NTHRP, 4) void crf_pair_kernel(const f16* __restrict__ qin,
                                                            const f16* __restrict__ u16,
                                                            const f16* __restrict__ wcA,
                                                            const f16* __restrict__ wcB16,
                                                            void* __restrict__ qout) {
    extern __shared__ __align__(16) f16 buf[];     // SHBYTES = 76800 B

    const int tid = threadIdx.x;          // 0..511
    const int ix = tid & (TW - 1);        // 0..31
    const int iyp = tid >> 5;             // 0..15 (pair row)

    // XCD band swizzle: 512 blocks; XCD (flat%8) owns 2 tile-rows per batch
    const int flat = blockIdx.x;
    const int band = flat & 7;
    const int within = flat >> 3;         // 0..63
    const int b = within >> 5;            // batch
    const int r = within & 31;
    const int x0 = (r & 15) * TW;
    const int y0 = (band * 2 + (r >> 4)) * TH;
    const int gx = x0 + ix;
    const int gy0 = y0 + 2 * iyp;         // pair base row
    const size_t plane = (size_t)HH * WW;

    // ---- phase 1: async stage 40x40 q halo (4-px, for 2 iterations) ----
    const f16* qbase = qin + (size_t)b * plane * CPAD;
    f16* lbase = &buf[0];
    for (int idx = tid; idx < SCHUNK; idx += NTHRP) {
        int px = idx / 3, h4 = idx - px * 3;
        int sly = px / SX, slx = px - sly * SX;
        int qy = refl(y0 - 4 + sly, HH);
        int qx = refl(x0 - 4 + slx, WW);
        const f16* g = qbase + ((size_t)(qy * WW + qx)) * CPAD + h4 * 8;
        __builtin_amdgcn_global_load_lds(
            (const __attribute__((address_space(1))) void*)g,
            (__attribute__((address_space(3))) void*)(lbase + (size_t)idx * 8),
            16, 0, 0);
    }

    // ---- inner pair weights + unary (registers, used by BOTH iterations) ----
    const size_t pix0 = (size_t)b * plane + (size_t)gy0 * WW + gx;
    const size_t pix1 = pix0 + WW;
    const half8* wpa = (const half8*)(wcA + pix0 * 24);
    half8 wa0 = wpa[0], wa1 = wpa[1], wa2 = wpa[2];
    f16 wal = wcB16[pix0];
    const half8* wpb = (const half8*)(wcA + pix1 * 24);
    half8 wb0 = wpb[0], wb1 = wpb[1], wb2 = wpb[2];
    f16 wbl = wcB16[pix1];
    const half8* upa = (const half8*)(u16 + pix0 * CPAD);
    half8 ua0 = upa[0], ua1 = upa[1], ua2 = upa[2];
    const half8* upb = (const half8*)(u16 + pix1 * CPAD);
    half8 ub0 = upb[0], ub1 = upb[1], ub2 = upb[2];

    // ---- ring pair (threads 0..135): coords + weights + unary for 2 stacked px ----
    // ring pairs: rly=0 (ext rows 0,1, 36 cols), rly=34 (ext rows 34,35, 36 cols),
    // rly in {2,4,..,32} x rlx in {0,1,34,35} (side columns)
    const bool has_ring = tid < RINGP;
    int rlx = 0, rly = 0;
    half8 wr0a = {}, wr1a = {}, wr2a = {}, wr0b = {}, wr1b = {}, wr2b = {};
    f16 wrla = (f16)0.f, wrlb = (f16)0.f;
    half8 ur0a = {}, ur1a = {}, ur2a = {}, ur0b = {}, ur1b = {}, ur2b = {};
    if (has_ring) {
        int t = tid;
        if (t < 36)      { rlx = t;      rly = 0;  }     // top 2 rows
        else if (t < 72) { rlx = t - 36; rly = 34; }     // bottom 2 rows
        else {                                            // side columns, rows 2..33
            t -= 72;                     // 0..63: 16 row-pairs x 4 cols
            int u2 = t >> 2;             // 0..15
            int c = t & 3;
            rly = 2 + 2 * u2;            // 2,4,..,32
            rlx = (c < 2) ? c : (c + 32);
        }
        int rgx = x0 + rlx - 2;
        int rgy0 = y0 + rly - 2;
        int cx  = min(max(rgx, 0), WW - 1);
        int cy0 = min(max(rgy0, 0), HH - 1);
        int cy1 = min(max(rgy0 + 1, 0), HH - 1);
        size_t rp0 = (size_t)b * plane + (size_t)cy0 * WW + cx;
        size_t rp1 = (size_t)b * plane + (size_t)cy1 * WW + cx;
        const half8* w0p = (const half8*)(wcA + rp0 * 24);
        wr0a = w0p[0]; wr1a = w0p[1]; wr2a = w0p[2];
        wrla = wcB16[rp0];
        const half8* w1p = (const half8*)(wcA + rp1 * 24);
        wr0b = w1p[0]; wr1b = w1p[1]; wr2b = w1p[2];
        wrlb = wcB16[rp1];
        const half8* u0p = (const half8*)(u16 + rp0 * CPAD);
        ur0a = u0p[0]; ur1a = u0p[1]; ur2a = u0p[2];
        const half8* u1p = (const half8*)(u16 + rp1 * CPAD);
        ur0b = u1p[0]; ur1b = u1p[1]; ur2b = u1p[2];
    }

    __syncthreads();   // staged q + register loads resident

    // ---- phase 2a: iteration k at ring pair (shared 6x5 tap reads) ----
    half8 qr0a, qr1a, qr2a, qr0b, qr1b, qr2b;
    if (has_ring) {
        half2v accA[11], accB[11];
#pragma unroll
        for (int j = 0; j < 11; j++) { accA[j] = (half2v){(f16)0.f, (f16)0.f}; accB[j] = accA[j]; }
        CONV_PAIR_STAGED(accA, accB, lbase, rly, rlx, SX,
                         wr0a, wr1a, wr2a, wrla, wr0b, wr1b, wr2b, wrlb);
        FINISH_PX(accA, ur0a, ur1a, ur2a, qr0a, qr1a, qr2a);
        FINISH_PX(accB, ur0b, ur1b, ur2b, qr0b, qr1b, qr2b);
    }

    // ---- phase 2b: iteration k at inner pair ----
    half8 qi0a, qi1a, qi2a, qi0b, qi1b, qi2b;
    {
        half2v accA[11], accB[11];
#pragma unroll
        for (int j = 0; j < 11; j++) { accA[j] = (half2v){(f16)0.f, (f16)0.f}; accB[j] = accA[j]; }
        CONV_PAIR_STAGED(accA, accB, lbase, 2 * iyp + 2, ix + 2, SX,
                         wa0, wa1, wa2, wal, wb0, wb1, wb2, wbl);
        FINISH_PX(accA, ua0, ua1, ua2, qi0a, qi1a, qi2a);
        FINISH_PX(accB, ub0, ub1, ub2, qi0b, qi1b, qi2b);
    }

    __syncthreads();   // all reads of staged q complete

    // ---- phase 3: park q' in LDS (reuse buf; layout [EPX][24], stride EX) ----
    {
        half8* d0 = (half8*)(lbase + ((size_t)(2 * iyp + 2) * EX + (ix + 2)) * CPAD);
        d0[0] = qi0a; d0[1] = qi1a; d0[2] = qi2a;
        half8* d1 = (half8*)(lbase + ((size_t)(2 * iyp + 3) * EX + (ix + 2)) * CPAD);
        d1[0] = qi0b; d1[1] = qi1b; d1[2] = qi2b;
        if (has_ring) {
            half8* e0 = (half8*)(lbase + ((size_t)rly * EX + rlx) * CPAD);
            e0[0] = qr0a; e0[1] = qr1a; e0[2] = qr2a;
            half8* e1 = (half8*)(lbase + ((size_t)(rly + 1) * EX + rlx) * CPAD);
            e1[0] = qr0b; e1[1] = qr1b; e1[2] = qr2b;
        }
    }

    __syncthreads();

    // ---- phase 4: iteration k+1 at inner pair (w,u from registers; reflected idx) ----
    {
        int ry_[6], rx_[5];
#pragma unroll
        for (int d = 0; d < 6; d++) ry_[d] = refl(gy0 + d - 2, HH) - (y0 - 2);
#pragma unroll
        for (int d = 0; d < 5; d++) rx_[d] = refl(gx + d - 2, WW) - (x0 - 2);
        half2v accA[11], accB[11];
#pragma unroll
        for (int j = 0; j < 11; j++) { accA[j] = (half2v){(f16)0.f, (f16)0.f}; accB[j] = accA[j]; }
        CONV_PAIR_IDX(accA, accB, lbase, ry_, rx_, EX,
                      wa0, wa1, wa2, wal, wb0, wb1, wb2, wbl);

        if (FINAL) {
            float* qo0 = (float*)qout + (size_t)b * NCH * plane + (size_t)gy0 * WW + gx;
            FINISH_PX_F32(accA, ua0, ua1, ua2, qo0, plane);
            float* qo1 = qo0 + WW;
            FINISH_PX_F32(accB, ub0, ub1, ub2, qo1, plane);
        } else {
            half8 o0, o1, o2;
            FINISH_PX(accA, ua0, ua1, ua2, o0, o1, o2);
            half8* qo0 = (half8*)((f16*)qout + pix0 * CPAD);
            qo0[0] = o0; qo0[1] = o1; qo0[2] = o2;
            half8 p0, p1, p2;
            FINISH_PX(accB, ub0, ub1, ub2, p0, p1, p2);
            half8* qo1 = (half8*)((f16*)qout + pix1 * CPAD);
            qo1[0] = p0; qo1[1] = p1; qo1[2] = p2;
        }
    }
}

extern "C" void kernel_launch(void* const* d_in, const int* in_sizes, int n_in,
                              void* d_out, int out_size, void* d_ws, size_t ws_size,
                              hipStream_t stream) {
    const float* unary = (const float*)d_in[0];   // B,21,512,512
    const float* image = (const float*)d_in[1];   // B,3,512,512
    const float* edges = (const float*)d_in[2];   // B,512,512
    float* out = (float*)d_out;                   // B,21,512,512 fp32

    const size_t plane = (size_t)HH * WW;
    char* ws = (char*)d_ws;
    f16* wcA = (f16*)ws;                                         // B*plane*24 f16 = 25.2 MB
    char* p1 = ws + sizeof(f16) * BATCH * plane * 24;
    f16* wcB16 = (f16*)p1;                                       // B*plane f16    =  1.0 MB
    char* p2 = p1 + sizeof(f16) * BATCH * plane;
    f16* u16 = (f16*)p2;                                         // 25.2 MB
    char* p3 = p2 + sizeof(f16) * BATCH * plane * CPAD;
    f16* qA = (f16*)p3;                                          // 25.2 MB
    f16* qB = qA + (size_t)BATCH * plane * CPAD;                 // 25.2 MB (total ~102 MB)

    // raise the dynamic-LDS cap once (76.8 KB > 64 KB default)
    static bool s_attr_done = false;
    if (!s_attr_done) {
        hipFuncSetAttribute((const void*)crf_pair_kernel<false>,
                            hipFuncAttributeMaxDynamicSharedMemorySize, SHBYTES);
        hipFuncSetAttribute((const void*)crf_pair_kernel<true>,
                            hipFuncAttributeMaxDynamicSharedMemorySize, SHBYTES);
        s_attr_done = true;
    }

    const int npix = BATCH * HH * WW;
    dim3 gridW(WW / TXW, HH / TYW, BATCH);
    dim3 blockW(TXW, TYW, 1);
    weights_kernel<<<gridW, blockW, 0, stream>>>(image, edges, wcA, wcB16);
    init_kernel<<<(npix + 255) / 256, 256, 0, stream>>>(unary, qA, u16);

    const int nblk = (WW / TW) * (HH / TH) * BATCH;   // 512
    f16* qa = qA;
    f16* qb = qB;
    const int npairs = NUM_ITERS / 2;                 // 5
    for (int it = 0; it < npairs - 1; it++) {
        crf_pair_kernel<false><<<nblk, NTHRP, SHBYTES, stream>>>(qa, u16, wcA, wcB16, (void*)qb);
        f16* t = qa; qa = qb; qb = t;
    }
    crf_pair_kernel<true><<<nblk, NTHRP, SHBYTES, stream>>>(qa, u16, wcA, wcB16, (void*)out);
}

// Round 4
// 351.424 us; speedup vs baseline: 1.6925x; 1.6925x over previous
//
#include <hip/hip_runtime.h>
#include <math.h>

#define BATCH 2
#define NCH 21
#define CPAD 24            // channels padded to 24 (48 B fp16 per pixel)
#define HH 512
#define WW 512
#define KS 5
#define RAD 2
#define NTAPS 25
#define NUM_ITERS 10

// weights-kernel tile geometry
#define TXW 32
#define TYW 8
#define HXW (TXW + 2*RAD)   // 36
#define HYW (TYW + 2*RAD)   // 12
#define HPXW (HXW * HYW)    // 432

// fused-pair kernel geometry: 32x32 inner tile, 512 threads, 2 y-stacked px/thread
#define TW 32
#define TH 32
#define NTHRP 512
#define SX 40               // staged tile (4-px halo for 2 iters)
#define SY 40
#define SPX (SX * SY)       // 1600
#define SCHUNK (SPX * 3)    // 4800 16-byte DMA chunks
#define SHBYTES (SPX * CPAD * 2)   // 76800 B dynamic LDS
#define EX 36               // extended (iter-1 output) region
#define EY 36
#define EPX (EX * EY)       // 1296
#define RINGP 136           // ring y-pairs covering the 272 ring pixels

typedef _Float16 f16;
typedef _Float16 half8 __attribute__((ext_vector_type(8)));
typedef _Float16 half2v __attribute__((ext_vector_type(2)));

__device__ __forceinline__ int refl(int i, int n) {
    if (i < 0) i = -i;
    if (i >= n) i = 2*n - 2 - i;
    return i;
}

// weight-element selector (t is a compile-time constant after unrolling)
#define WSEL(h0, h1, h2, hl, t) \
    ((t) < 8 ? (h0)[(t)] : (t) < 16 ? (h1)[(t) - 8] : (t) < 24 ? (h2)[(t) - 16] : (hl))

// ---------------- Kernel A: combined normalized weights (unchanged) ----------------
__global__ __launch_bounds__(256) void weights_kernel(const float* __restrict__ image,
                                                      const float* __restrict__ edges,
                                                      f16* __restrict__ wcA,
                                                      f16* __restrict__ wcB16) {
    __shared__ float sr_[HYW][HXW];
    __shared__ float sg_[HYW][HXW];
    __shared__ float sb_[HYW][HXW];
    __shared__ float se_[HYW][HXW];

    const int tx = threadIdx.x;
    const int ty = threadIdx.y;
    const int tid = ty * TXW + tx;
    const int x0 = blockIdx.x * TXW;
    const int y0 = blockIdx.y * TYW;
    const int b = blockIdx.z;
    const int x = x0 + tx;
    const int y = y0 + ty;
    const size_t plane = (size_t)HH * WW;
    const float* img = image + (size_t)b * 3 * plane;
    const float* edg = edges + (size_t)b * plane;

    for (int i = tid; i < HPXW; i += TXW * TYW) {
        int ly = i / HXW, lx = i - ly * HXW;
        int gy = refl(y0 + ly - RAD, HH);
        int gx = refl(x0 + lx - RAD, WW);
        int g = gy * WW + gx;
        sr_[ly][lx] = img[g];
        sg_[ly][lx] = img[plane + g];
        sb_[ly][lx] = img[2 * plane + g];
        se_[ly][lx] = edg[g];
    }
    __syncthreads();

    float gs[3];
    gs[0] = 1.0f; gs[1] = __expf(-1.0f / 50.0f); gs[2] = __expf(-4.0f / 50.0f);
    float gb[3];
    gb[0] = 1.0f; gb[1] = __expf(-2.0f); gb[2] = __expf(-8.0f);
    float gbs = gb[0] + 2.0f * (gb[1] + gb[2]);
    gb[0] /= gbs; gb[1] /= gbs; gb[2] /= gbs;

    const float r0 = sr_[ty + RAD][tx + RAD];
    const float g0 = sg_[ty + RAD][tx + RAD];
    const float b0 = sb_[ty + RAD][tx + RAD];
    const float e0 = se_[ty + RAD][tx + RAD];

    float wr[NTAPS], we[NTAPS];
    float sr = 0.f, se = 0.f;
#pragma unroll
    for (int dy = 0; dy < KS; dy++) {
#pragma unroll
        for (int dx = 0; dx < KS; dx++) {
            float sp = gs[abs(dy - RAD)] * gs[abs(dx - RAD)];
            float d = fabsf(sr_[ty + dy][tx + dx] - r0)
                    + fabsf(sg_[ty + dy][tx + dx] - g0)
                    + fabsf(sb_[ty + dy][tx + dx] - b0);
            float w1 = sp * __expf(-2.0f * d * d);
            float de = fabsf(se_[ty + dy][tx + dx] - e0);
            float w2 = sp * __expf(-2.0f * de * de);
            wr[dy * KS + dx] = w1;
            we[dy * KS + dx] = w2;
            sr += w1;
            se += w2;
        }
    }
    float isr = 1.0f / sr, ise = 1.0f / se;
    float wt[NTAPS];
#pragma unroll
    for (int t = 0; t < NTAPS; t++) {
        int dy = t / KS, dx = t % KS;
        float g2 = gb[abs(dy - RAD)] * gb[abs(dx - RAD)];
        wt[t] = g2 + wr[t] * isr + we[t] * ise;
    }
    const size_t pixoff = (size_t)b * plane + (size_t)y * WW + x;
    half8* wo = (half8*)(wcA + pixoff * 24);
#pragma unroll
    for (int g = 0; g < 3; g++) {
        half8 v;
#pragma unroll
        for (int k = 0; k < 8; k++) v[k] = (f16)wt[g * 8 + k];
        wo[g] = v;
    }
    wcB16[pixoff] = (f16)wt[24];
}

// ---------------- Kernel B: initial softmax -> interleaved fp16 q + fp16 unary (unchanged) ----------------
__global__ void init_kernel(const float* __restrict__ unary,
                            f16* __restrict__ q,
                            f16* __restrict__ u16) {
    int idx = blockIdx.x * blockDim.x + threadIdx.x;
    if (idx >= BATCH * HH * WW) return;
    int p = idx % (HH * WW);
    int b = idx / (HH * WW);
    const size_t plane = (size_t)HH * WW;
    const float* u = unary + (size_t)b * NCH * plane + p;
    float l[CPAD];
    float m = -1e30f;
#pragma unroll
    for (int c = 0; c < NCH; c++) { l[c] = u[c * plane]; m = fmaxf(m, l[c]); }
    l[21] = 0.f; l[22] = 0.f; l[23] = 0.f;

    half8* uo = (half8*)(u16 + ((size_t)b * plane + p) * CPAD);
#pragma unroll
    for (int g = 0; g < 3; g++) {
        half8 v;
#pragma unroll
        for (int k = 0; k < 8; k++) v[k] = (f16)l[g * 8 + k];
        uo[g] = v;
    }

    float s = 0.f;
    float e[CPAD];
#pragma unroll
    for (int c = 0; c < NCH; c++) { e[c] = __expf(l[c] - m); s += e[c]; }
    float is = 1.0f / s;
    e[21] = 0.f; e[22] = 0.f; e[23] = 0.f;
    half8* qo = (half8*)(q + ((size_t)b * plane + p) * CPAD);
#pragma unroll
    for (int g = 0; g < 3; g++) {
        half8 v;
#pragma unroll
        for (int k = 0; k < 8; k++) v[k] = (f16)(e[g * 8 + k] * is);
        qo[g] = v;
    }
}

// 11 packed MACs (21 channels + 1 pad) for one pixel from one tap position
#define PK11(acc2, wv_, v0, v1, v2) do {                                                            \
    acc2[0]  = __builtin_elementwise_fma(wv_, __builtin_shufflevector(v0, v0, 0, 1), acc2[0]);      \
    acc2[1]  = __builtin_elementwise_fma(wv_, __builtin_shufflevector(v0, v0, 2, 3), acc2[1]);      \
    acc2[2]  = __builtin_elementwise_fma(wv_, __builtin_shufflevector(v0, v0, 4, 5), acc2[2]);      \
    acc2[3]  = __builtin_elementwise_fma(wv_, __builtin_shufflevector(v0, v0, 6, 7), acc2[3]);      \
    acc2[4]  = __builtin_elementwise_fma(wv_, __builtin_shufflevector(v1, v1, 0, 1), acc2[4]);      \
    acc2[5]  = __builtin_elementwise_fma(wv_, __builtin_shufflevector(v1, v1, 2, 3), acc2[5]);      \
    acc2[6]  = __builtin_elementwise_fma(wv_, __builtin_shufflevector(v1, v1, 4, 5), acc2[6]);      \
    acc2[7]  = __builtin_elementwise_fma(wv_, __builtin_shufflevector(v1, v1, 6, 7), acc2[7]);      \
    acc2[8]  = __builtin_elementwise_fma(wv_, __builtin_shufflevector(v2, v2, 0, 1), acc2[8]);      \
    acc2[9]  = __builtin_elementwise_fma(wv_, __builtin_shufflevector(v2, v2, 2, 3), acc2[9]);      \
    acc2[10] = __builtin_elementwise_fma(wv_, __builtin_shufflevector(v2, v2, 4, 5), acc2[10]);     \
} while (0)

// paired conv over a y-stacked pixel pair: 6 rows x 5 cols, each 48B tap read shared by
// both pixels (rows 1..4); pixel A uses row index r, pixel B uses r-1.
// per-pixel accumulation order is identical to the unpaired version (dy outer, dx inner).
#define CONV_PAIR_STAGED(accA, accB, lds, row0, col0, stride,                                       \
                         WA0, WA1, WA2, WAL, WB0, WB1, WB2, WBL)                                    \
    {                                                                                               \
        _Pragma("unroll")                                                                           \
        for (int r_ = 0; r_ < 6; r_++) {                                                            \
            _Pragma("unroll")                                                                       \
            for (int dx_ = 0; dx_ < 5; dx_++) {                                                     \
                const f16* tp_ = (lds) + ((size_t)((row0) + r_) * (stride) + (col0) + dx_) * CPAD;  \
                half8 v0_ = *(const half8*)(tp_);                                                   \
                half8 v1_ = *(const half8*)(tp_ + 8);                                               \
                half8 v2_ = *(const half8*)(tp_ + 16);                                              \
                if (r_ < 5) {                                                                       \
                    const f16 wA_ = WSEL(WA0, WA1, WA2, WAL, r_ * 5 + dx_);                         \
                    const half2v wvA_ = {wA_, wA_};                                                 \
                    PK11(accA, wvA_, v0_, v1_, v2_);                                                \
                }                                                                                   \
                if (r_ >= 1) {                                                                      \
                    const f16 wB_ = WSEL(WB0, WB1, WB2, WBL, (r_ - 1) * 5 + dx_);                   \
                    const half2v wvB_ = {wB_, wB_};                                                 \
                    PK11(accB, wvB_, v0_, v1_, v2_);                                                \
                }                                                                                   \
            }                                                                                       \
        }                                                                                           \
    }

// same but with per-row / per-col index arrays (reflected indexing for iteration 2)
#define CONV_PAIR_IDX(accA, accB, lds, ryArr, rxArr, stride,                                        \
                      WA0, WA1, WA2, WAL, WB0, WB1, WB2, WBL)                                       \
    {                                                                                               \
        _Pragma("unroll")                                                                           \
        for (int r_ = 0; r_ < 6; r_++) {                                                            \
            _Pragma("unroll")                                                                       \
            for (int dx_ = 0; dx_ < 5; dx_++) {                                                     \
                const f16* tp_ = (lds) + ((size_t)(ryArr)[r_] * (stride) + (rxArr)[dx_]) * CPAD;    \
                half8 v0_ = *(const half8*)(tp_);                                                   \
                half8 v1_ = *(const half8*)(tp_ + 8);                                               \
                half8 v2_ = *(const half8*)(tp_ + 16);                                              \
                if (r_ < 5) {                                                                       \
                    const f16 wA_ = WSEL(WA0, WA1, WA2, WAL, r_ * 5 + dx_);                         \
                    const half2v wvA_ = {wA_, wA_};                                                 \
                    PK11(accA, wvA_, v0_, v1_, v2_);                                                \
                }                                                                                   \
                if (r_ >= 1) {                                                                      \
                    const f16 wB_ = WSEL(WB0, WB1, WB2, WBL, (r_ - 1) * 5 + dx_);                   \
                    const half2v wvB_ = {wB_, wB_};                                                 \
                    PK11(accB, wvB_, v0_, v1_, v2_);                                                \
                }                                                                                   \
            }                                                                                       \
        }                                                                                           \
    }

// logits: l[c] = u[c] - acc2 (promote f16 acc to f32 here)
#define LOGITS_FROM_PK(l, acc2, U0, U1, U2)                                            \
    {                                                                                  \
        _Pragma("unroll")                                                              \
        for (int j = 0; j < 10; j++) {                                                 \
            l[2 * j]     = -(float)acc2[j][0];                                         \
            l[2 * j + 1] = -(float)acc2[j][1];                                         \
        }                                                                              \
        l[20] = -(float)acc2[10][0];                                                   \
        _Pragma("unroll")                                                              \
        for (int k = 0; k < 8; k++) l[k] += (float)U0[k];                              \
        _Pragma("unroll")                                                              \
        for (int k = 0; k < 8; k++) l[8 + k] += (float)U1[k];                          \
        _Pragma("unroll")                                                              \
        for (int k = 0; k < 5; k++) l[16 + k] += (float)U2[k];                         \
    }

// logits -> softmax -> packed f16 q' triple (fully inline; no address-taken temps
// crossing a call boundary)
#define FINISH_PX(acc2, U0, U1, U2, o0, o1, o2)                                        \
    {                                                                                  \
        float l_[NCH];                                                                 \
        LOGITS_FROM_PK(l_, acc2, U0, U1, U2);                                          \
        float m_ = l_[0];                                                              \
        _Pragma("unroll")                                                              \
        for (int c = 1; c < NCH; c++) m_ = fmaxf(m_, l_[c]);                           \
        float s_ = 0.f;                                                                \
        _Pragma("unroll")                                                              \
        for (int c = 0; c < NCH; c++) { l_[c] = __expf(l_[c] - m_); s_ += l_[c]; }     \
        float is_ = 1.0f / s_;                                                         \
        _Pragma("unroll")                                                              \
        for (int k = 0; k < 8; k++) (o0)[k] = (f16)(l_[k] * is_);                      \
        _Pragma("unroll")                                                              \
        for (int k = 0; k < 8; k++) (o1)[k] = (f16)(l_[8 + k] * is_);                  \
        _Pragma("unroll")                                                              \
        for (int k = 0; k < 5; k++) (o2)[k] = (f16)(l_[16 + k] * is_);                 \
        (o2)[5] = (f16)0.f; (o2)[6] = (f16)0.f; (o2)[7] = (f16)0.f;                    \
    }

// logits -> softmax -> strided fp32 store (final iteration)
#define FINISH_PX_F32(acc2, U0, U1, U2, qo, plane)                                     \
    {                                                                                  \
        float l_[NCH];                                                                 \
        LOGITS_FROM_PK(l_, acc2, U0, U1, U2);                                          \
        float m_ = l_[0];                                                              \
        _Pragma("unroll")                                                              \
        for (int c = 1; c < NCH; c++) m_ = fmaxf(m_, l_[c]);                           \
        float s_ = 0.f;                                                                \
        _Pragma("unroll")                                                              \
        for (int c = 0; c < NCH; c++) { l_[c] = __expf(l_[c] - m_); s_ += l_[c]; }     \
        float is_ = 1.0f / s_;                                                         \
        _Pragma("unroll")                                                              \
        for (int c = 0; c < NCH; c++) (qo)[c * (plane)] = l_[c] * is_;                 \
    }

// ---------------- Kernel C: TWO fused CRF iterations, 32x32 tile, 2 y-stacked px/thread ----
// 512 threads (8 waves), 76.8 KB dynamic LDS -> 2 blocks/CU = 16 waves/CU, grid 512 = all
// blocks co-resident (no tail generation).
// __launch_bounds__(512, 2): empirically (R2 A/B) arg-2 acts CUDA-style (min BLOCKS/CU);
// (512,4) capped VGPR at 64 and spilled ~250 MB/launch. 2 blocks -> cap 128, which R1
// proved is exactly the pair body's natural allocation. LDS limits residency to 2 anyway.
template <bool FINAL>
__global__ __launch_bounds__(NTHRP, 2) void crf_pair_kernel(const f16* __restrict__ qin,
                                                            const f16* __restrict__ u16,
                                                            const f16* __restrict__ wcA,
                                                            const f16* __restrict__ wcB16,
                                                            void* __restrict__ qout) {
    extern __shared__ __align__(16) f16 buf[];     // SHBYTES = 76800 B

    const int tid = threadIdx.x;          // 0..511
    const int ix = tid & (TW - 1);        // 0..31
    const int iyp = tid >> 5;             // 0..15 (pair row)

    // XCD band swizzle: 512 blocks; XCD (flat%8) owns 2 tile-rows per batch
    const int flat = blockIdx.x;
    const int band = flat & 7;
    const int within = flat >> 3;         // 0..63
    const int b = within >> 5;            // batch
    const int r = within & 31;
    const int x0 = (r & 15) * TW;
    const int y0 = (band * 2 + (r >> 4)) * TH;
    const int gx = x0 + ix;
    const int gy0 = y0 + 2 * iyp;         // pair base row
    const size_t plane = (size_t)HH * WW;

    // ---- phase 1: async stage 40x40 q halo (4-px, for 2 iterations) ----
    const f16* qbase = qin + (size_t)b * plane * CPAD;
    f16* lbase = &buf[0];
    for (int idx = tid; idx < SCHUNK; idx += NTHRP) {
        int px = idx / 3, h4 = idx - px * 3;
        int sly = px / SX, slx = px - sly * SX;
        int qy = refl(y0 - 4 + sly, HH);
        int qx = refl(x0 - 4 + slx, WW);
        const f16* g = qbase + ((size_t)(qy * WW + qx)) * CPAD + h4 * 8;
        __builtin_amdgcn_global_load_lds(
            (const __attribute__((address_space(1))) void*)g,
            (__attribute__((address_space(3))) void*)(lbase + (size_t)idx * 8),
            16, 0, 0);
    }

    // ---- inner pair weights + unary (registers, used by BOTH iterations) ----
    const size_t pix0 = (size_t)b * plane + (size_t)gy0 * WW + gx;
    const size_t pix1 = pix0 + WW;
    const half8* wpa = (const half8*)(wcA + pix0 * 24);
    half8 wa0 = wpa[0], wa1 = wpa[1], wa2 = wpa[2];
    f16 wal = wcB16[pix0];
    const half8* wpb = (const half8*)(wcA + pix1 * 24);
    half8 wb0 = wpb[0], wb1 = wpb[1], wb2 = wpb[2];
    f16 wbl = wcB16[pix1];
    const half8* upa = (const half8*)(u16 + pix0 * CPAD);
    half8 ua0 = upa[0], ua1 = upa[1], ua2 = upa[2];
    const half8* upb = (const half8*)(u16 + pix1 * CPAD);
    half8 ub0 = upb[0], ub1 = upb[1], ub2 = upb[2];

    // ---- ring pair (threads 0..135): coords + weights + unary for 2 stacked px ----
    // ring pairs: rly=0 (ext rows 0,1, 36 cols), rly=34 (ext rows 34,35, 36 cols),
    // rly in {2,4,..,32} x rlx in {0,1,34,35} (side columns)
    const bool has_ring = tid < RINGP;
    int rlx = 0, rly = 0;
    half8 wr0a = {}, wr1a = {}, wr2a = {}, wr0b = {}, wr1b = {}, wr2b = {};
    f16 wrla = (f16)0.f, wrlb = (f16)0.f;
    half8 ur0a = {}, ur1a = {}, ur2a = {}, ur0b = {}, ur1b = {}, ur2b = {};
    if (has_ring) {
        int t = tid;
        if (t < 36)      { rlx = t;      rly = 0;  }     // top 2 rows
        else if (t < 72) { rlx = t - 36; rly = 34; }     // bottom 2 rows
        else {                                            // side columns, rows 2..33
            t -= 72;                     // 0..63: 16 row-pairs x 4 cols
            int u2 = t >> 2;             // 0..15
            int c = t & 3;
            rly = 2 + 2 * u2;            // 2,4,..,32
            rlx = (c < 2) ? c : (c + 32);
        }
        int rgx = x0 + rlx - 2;
        int rgy0 = y0 + rly - 2;
        int cx  = min(max(rgx, 0), WW - 1);
        int cy0 = min(max(rgy0, 0), HH - 1);
        int cy1 = min(max(rgy0 + 1, 0), HH - 1);
        size_t rp0 = (size_t)b * plane + (size_t)cy0 * WW + cx;
        size_t rp1 = (size_t)b * plane + (size_t)cy1 * WW + cx;
        const half8* w0p = (const half8*)(wcA + rp0 * 24);
        wr0a = w0p[0]; wr1a = w0p[1]; wr2a = w0p[2];
        wrla = wcB16[rp0];
        const half8* w1p = (const half8*)(wcA + rp1 * 24);
        wr0b = w1p[0]; wr1b = w1p[1]; wr2b = w1p[2];
        wrlb = wcB16[rp1];
        const half8* u0p = (const half8*)(u16 + rp0 * CPAD);
        ur0a = u0p[0]; ur1a = u0p[1]; ur2a = u0p[2];
        const half8* u1p = (const half8*)(u16 + rp1 * CPAD);
        ur0b = u1p[0]; ur1b = u1p[1]; ur2b = u1p[2];
    }

    __syncthreads();   // staged q + register loads resident

    // ---- phase 2a: iteration k at ring pair (shared 6x5 tap reads) ----
    half8 qr0a, qr1a, qr2a, qr0b, qr1b, qr2b;
    if (has_ring) {
        half2v accA[11], accB[11];
#pragma unroll
        for (int j = 0; j < 11; j++) { accA[j] = (half2v){(f16)0.f, (f16)0.f}; accB[j] = accA[j]; }
        CONV_PAIR_STAGED(accA, accB, lbase, rly, rlx, SX,
                         wr0a, wr1a, wr2a, wrla, wr0b, wr1b, wr2b, wrlb);
        FINISH_PX(accA, ur0a, ur1a, ur2a, qr0a, qr1a, qr2a);
        FINISH_PX(accB, ur0b, ur1b, ur2b, qr0b, qr1b, qr2b);
    }

    // ---- phase 2b: iteration k at inner pair ----
    half8 qi0a, qi1a, qi2a, qi0b, qi1b, qi2b;
    {
        half2v accA[11], accB[11];
#pragma unroll
        for (int j = 0; j < 11; j++) { accA[j] = (half2v){(f16)0.f, (f16)0.f}; accB[j] = accA[j]; }
        CONV_PAIR_STAGED(accA, accB, lbase, 2 * iyp + 2, ix + 2, SX,
                         wa0, wa1, wa2, wal, wb0, wb1, wb2, wbl);
        FINISH_PX(accA, ua0, ua1, ua2, qi0a, qi1a, qi2a);
        FINISH_PX(accB, ub0, ub1, ub2, qi0b, qi1b, qi2b);
    }

    __syncthreads();   // all reads of staged q complete

    // ---- phase 3: park q' in LDS (reuse buf; layout [EPX][24], stride EX) ----
    {
        half8* d0 = (half8*)(lbase + ((size_t)(2 * iyp + 2) * EX + (ix + 2)) * CPAD);
        d0[0] = qi0a; d0[1] = qi1a; d0[2] = qi2a;
        half8* d1 = (half8*)(lbase + ((size_t)(2 * iyp + 3) * EX + (ix + 2)) * CPAD);
        d1[0] = qi0b; d1[1] = qi1b; d1[2] = qi2b;
        if (has_ring) {
            half8* e0 = (half8*)(lbase + ((size_t)rly * EX + rlx) * CPAD);
            e0[0] = qr0a; e0[1] = qr1a; e0[2] = qr2a;
            half8* e1 = (half8*)(lbase + ((size_t)(rly + 1) * EX + rlx) * CPAD);
            e1[0] = qr0b; e1[1] = qr1b; e1[2] = qr2b;
        }
    }

    __syncthreads();

    // ---- phase 4: iteration k+1 at inner pair (w,u from registers; reflected idx) ----
    {
        int ry_[6], rx_[5];
#pragma unroll
        for (int d = 0; d < 6; d++) ry_[d] = refl(gy0 + d - 2, HH) - (y0 - 2);
#pragma unroll
        for (int d = 0; d < 5; d++) rx_[d] = refl(gx + d - 2, WW) - (x0 - 2);
        half2v accA[11], accB[11];
#pragma unroll
        for (int j = 0; j < 11; j++) { accA[j] = (half2v){(f16)0.f, (f16)0.f}; accB[j] = accA[j]; }
        CONV_PAIR_IDX(accA, accB, lbase, ry_, rx_, EX,
                      wa0, wa1, wa2, wal, wb0, wb1, wb2, wbl);

        if (FINAL) {
            float* qo0 = (float*)qout + (size_t)b * NCH * plane + (size_t)gy0 * WW + gx;
            FINISH_PX_F32(accA, ua0, ua1, ua2, qo0, plane);
            float* qo1 = qo0 + WW;
            FINISH_PX_F32(accB, ub0, ub1, ub2, qo1, plane);
        } else {
            half8 o0, o1, o2;
            FINISH_PX(accA, ua0, ua1, ua2, o0, o1, o2);
            half8* qo0 = (half8*)((f16*)qout + pix0 * CPAD);
            qo0[0] = o0; qo0[1] = o1; qo0[2] = o2;
            half8 p0, p1, p2;
            FINISH_PX(accB, ub0, ub1, ub2, p0, p1, p2);
            half8* qo1 = (half8*)((f16*)qout + pix1 * CPAD);
            qo1[0] = p0; qo1[1] = p1; qo1[2] = p2;
        }
    }
}

extern "C" void kernel_launch(void* const* d_in, const int* in_sizes, int n_in,
                              void* d_out, int out_size, void* d_ws, size_t ws_size,
                              hipStream_t stream) {
    const float* unary = (const float*)d_in[0];   // B,21,512,512
    const float* image = (const float*)d_in[1];   // B,3,512,512
    const float* edges = (const float*)d_in[2];   // B,512,512
    float* out = (float*)d_out;                   // B,21,512,512 fp32

    const size_t plane = (size_t)HH * WW;
    char* ws = (char*)d_ws;
    f16* wcA = (f16*)ws;                                         // B*plane*24 f16 = 25.2 MB
    char* p1 = ws + sizeof(f16) * BATCH * plane * 24;
    f16* wcB16 = (f16*)p1;                                       // B*plane f16    =  1.0 MB
    char* p2 = p1 + sizeof(f16) * BATCH * plane;
    f16* u16 = (f16*)p2;                                         // 25.2 MB
    char* p3 = p2 + sizeof(f16) * BATCH * plane * CPAD;
    f16* qA = (f16*)p3;                                          // 25.2 MB
    f16* qB = qA + (size_t)BATCH * plane * CPAD;                 // 25.2 MB (total ~102 MB)

    // raise the dynamic-LDS cap once (76.8 KB > 64 KB default)
    static bool s_attr_done = false;
    if (!s_attr_done) {
        hipFuncSetAttribute((const void*)crf_pair_kernel<false>,
                            hipFuncAttributeMaxDynamicSharedMemorySize, SHBYTES);
        hipFuncSetAttribute((const void*)crf_pair_kernel<true>,
                            hipFuncAttributeMaxDynamicSharedMemorySize, SHBYTES);
        s_attr_done = true;
    }

    const int npix = BATCH * HH * WW;
    dim3 gridW(WW / TXW, HH / TYW, BATCH);
    dim3 blockW(TXW, TYW, 1);
    weights_kernel<<<gridW, blockW, 0, stream>>>(image, edges, wcA, wcB16);
    init_kernel<<<(npix + 255) / 256, 256, 0, stream>>>(unary, qA, u16);

    const int nblk = (WW / TW) * (HH / TH) * BATCH;   // 512
    f16* qa = qA;
    f16* qb = qB;
    const int npairs = NUM_ITERS / 2;                 // 5
    for (int it = 0; it < npairs - 1; it++) {
        crf_pair_kernel<false><<<nblk, NTHRP, SHBYTES, stream>>>(qa, u16, wcA, wcB16, (void*)qb);
        f16* t = qa; qa = qb; qb = t;
    }
    crf_pair_kernel<true><<<nblk, NTHRP, SHBYTES, stream>>>(qa, u16, wcA, wcB16, (void*)out);
}

// Round 5
// 326.844 us; speedup vs baseline: 1.8198x; 1.0752x over previous
//
#include <hip/hip_runtime.h>
#include <math.h>

#define BATCH 2
#define NCH 21
#define CPAD 24            // channels padded to 24 (48 B fp16 per pixel)
#define HH 512
#define WW 512
#define KS 5
#define RAD 2
#define NTAPS 25
#define NUM_ITERS 10

// weights-kernel tile geometry
#define TXW 32
#define TYW 8
#define HXW (TXW + 2*RAD)   // 36
#define HYW (TYW + 2*RAD)   // 12
#define HPXW (HXW * HYW)    // 432

// fused-pair kernel geometry: 32x32 inner tile, 1024 threads, 1 px/thread (proven body)
#define TW 32
#define TH 32
#define NTHR 1024
#define SX 40               // staged tile (4-px halo for 2 iters)
#define SY 40
#define SPX (SX * SY)       // 1600
#define SCHUNK (SPX * 3)    // 4800 16-byte DMA chunks (4800 = 1024*4 + 704; 704%64==0, wave-granular tail)
#define SHBYTES (SPX * CPAD * 2)   // 76800 B dynamic LDS -> 2 blocks/CU
#define EX 36               // extended (iter-1 output) region
#define EY 36
#define EPX (EX * EY)       // 1296
#define RING (EPX - TW*TH)  // 272 ring pixels

typedef _Float16 f16;
typedef _Float16 half8 __attribute__((ext_vector_type(8)));
typedef _Float16 half2v __attribute__((ext_vector_type(2)));

__device__ __forceinline__ int refl(int i, int n) {
    if (i < 0) i = -i;
    if (i >= n) i = 2*n - 2 - i;
    return i;
}

// weight-element selector (t is a compile-time constant after unrolling)
#define WSEL(h0, h1, h2, hl, t) \
    ((t) < 8 ? (h0)[(t)] : (t) < 16 ? (h1)[(t) - 8] : (t) < 24 ? (h2)[(t) - 16] : (hl))

// ---------------- Kernel A: combined normalized weights (unchanged) ----------------
__global__ __launch_bounds__(256) void weights_kernel(const float* __restrict__ image,
                                                      const float* __restrict__ edges,
                                                      f16* __restrict__ wcA,
                                                      f16* __restrict__ wcB16) {
    __shared__ float sr_[HYW][HXW];
    __shared__ float sg_[HYW][HXW];
    __shared__ float sb_[HYW][HXW];
    __shared__ float se_[HYW][HXW];

    const int tx = threadIdx.x;
    const int ty = threadIdx.y;
    const int tid = ty * TXW + tx;
    const int x0 = blockIdx.x * TXW;
    const int y0 = blockIdx.y * TYW;
    const int b = blockIdx.z;
    const int x = x0 + tx;
    const int y = y0 + ty;
    const size_t plane = (size_t)HH * WW;
    const float* img = image + (size_t)b * 3 * plane;
    const float* edg = edges + (size_t)b * plane;

    for (int i = tid; i < HPXW; i += TXW * TYW) {
        int ly = i / HXW, lx = i - ly * HXW;
        int gy = refl(y0 + ly - RAD, HH);
        int gx = refl(x0 + lx - RAD, WW);
        int g = gy * WW + gx;
        sr_[ly][lx] = img[g];
        sg_[ly][lx] = img[plane + g];
        sb_[ly][lx] = img[2 * plane + g];
        se_[ly][lx] = edg[g];
    }
    __syncthreads();

    float gs[3];
    gs[0] = 1.0f; gs[1] = __expf(-1.0f / 50.0f); gs[2] = __expf(-4.0f / 50.0f);
    float gb[3];
    gb[0] = 1.0f; gb[1] = __expf(-2.0f); gb[2] = __expf(-8.0f);
    float gbs = gb[0] + 2.0f * (gb[1] + gb[2]);
    gb[0] /= gbs; gb[1] /= gbs; gb[2] /= gbs;

    const float r0 = sr_[ty + RAD][tx + RAD];
    const float g0 = sg_[ty + RAD][tx + RAD];
    const float b0 = sb_[ty + RAD][tx + RAD];
    const float e0 = se_[ty + RAD][tx + RAD];

    float wr[NTAPS], we[NTAPS];
    float sr = 0.f, se = 0.f;
#pragma unroll
    for (int dy = 0; dy < KS; dy++) {
#pragma unroll
        for (int dx = 0; dx < KS; dx++) {
            float sp = gs[abs(dy - RAD)] * gs[abs(dx - RAD)];
            float d = fabsf(sr_[ty + dy][tx + dx] - r0)
                    + fabsf(sg_[ty + dy][tx + dx] - g0)
                    + fabsf(sb_[ty + dy][tx + dx] - b0);
            float w1 = sp * __expf(-2.0f * d * d);
            float de = fabsf(se_[ty + dy][tx + dx] - e0);
            float w2 = sp * __expf(-2.0f * de * de);
            wr[dy * KS + dx] = w1;
            we[dy * KS + dx] = w2;
            sr += w1;
            se += w2;
        }
    }
    float isr = 1.0f / sr, ise = 1.0f / se;
    float wt[NTAPS];
#pragma unroll
    for (int t = 0; t < NTAPS; t++) {
        int dy = t / KS, dx = t % KS;
        float g2 = gb[abs(dy - RAD)] * gb[abs(dx - RAD)];
        wt[t] = g2 + wr[t] * isr + we[t] * ise;
    }
    const size_t pixoff = (size_t)b * plane + (size_t)y * WW + x;
    half8* wo = (half8*)(wcA + pixoff * 24);
#pragma unroll
    for (int g = 0; g < 3; g++) {
        half8 v;
#pragma unroll
        for (int k = 0; k < 8; k++) v[k] = (f16)wt[g * 8 + k];
        wo[g] = v;
    }
    wcB16[pixoff] = (f16)wt[24];
}

// ---------------- Kernel B: initial softmax -> interleaved fp16 q + fp16 unary (unchanged) ----------------
__global__ void init_kernel(const float* __restrict__ unary,
                            f16* __restrict__ q,
                            f16* __restrict__ u16) {
    int idx = blockIdx.x * blockDim.x + threadIdx.x;
    if (idx >= BATCH * HH * WW) return;
    int p = idx % (HH * WW);
    int b = idx / (HH * WW);
    const size_t plane = (size_t)HH * WW;
    const float* u = unary + (size_t)b * NCH * plane + p;
    float l[CPAD];
    float m = -1e30f;
#pragma unroll
    for (int c = 0; c < NCH; c++) { l[c] = u[c * plane]; m = fmaxf(m, l[c]); }
    l[21] = 0.f; l[22] = 0.f; l[23] = 0.f;

    half8* uo = (half8*)(u16 + ((size_t)b * plane + p) * CPAD);
#pragma unroll
    for (int g = 0; g < 3; g++) {
        half8 v;
#pragma unroll
        for (int k = 0; k < 8; k++) v[k] = (f16)l[g * 8 + k];
        uo[g] = v;
    }

    float s = 0.f;
    float e[CPAD];
#pragma unroll
    for (int c = 0; c < NCH; c++) { e[c] = __expf(l[c] - m); s += e[c]; }
    float is = 1.0f / s;
    e[21] = 0.f; e[22] = 0.f; e[23] = 0.f;
    half8* qo = (half8*)(q + ((size_t)b * plane + p) * CPAD);
#pragma unroll
    for (int g = 0; g < 3; g++) {
        half8 v;
#pragma unroll
        for (int k = 0; k < 8; k++) v[k] = (f16)(e[g * 8 + k] * is);
        qo[g] = v;
    }
}

// 11 packed MACs (21 channels + 1 pad) for one pixel from one tap position
#define PK11(acc2, wv_, v0, v1, v2) do {                                                            \
    acc2[0]  = __builtin_elementwise_fma(wv_, __builtin_shufflevector(v0, v0, 0, 1), acc2[0]);      \
    acc2[1]  = __builtin_elementwise_fma(wv_, __builtin_shufflevector(v0, v0, 2, 3), acc2[1]);      \
    acc2[2]  = __builtin_elementwise_fma(wv_, __builtin_shufflevector(v0, v0, 4, 5), acc2[2]);      \
    acc2[3]  = __builtin_elementwise_fma(wv_, __builtin_shufflevector(v0, v0, 6, 7), acc2[3]);      \
    acc2[4]  = __builtin_elementwise_fma(wv_, __builtin_shufflevector(v1, v1, 0, 1), acc2[4]);      \
    acc2[5]  = __builtin_elementwise_fma(wv_, __builtin_shufflevector(v1, v1, 2, 3), acc2[5]);      \
    acc2[6]  = __builtin_elementwise_fma(wv_, __builtin_shufflevector(v1, v1, 4, 5), acc2[6]);      \
    acc2[7]  = __builtin_elementwise_fma(wv_, __builtin_shufflevector(v1, v1, 6, 7), acc2[7]);      \
    acc2[8]  = __builtin_elementwise_fma(wv_, __builtin_shufflevector(v2, v2, 0, 1), acc2[8]);      \
    acc2[9]  = __builtin_elementwise_fma(wv_, __builtin_shufflevector(v2, v2, 2, 3), acc2[9]);      \
    acc2[10] = __builtin_elementwise_fma(wv_, __builtin_shufflevector(v2, v2, 4, 5), acc2[10]);     \
} while (0)

// single-px 25-tap conv (the proven R0 baseline inner loop)
#define CONV_ACC_PK(acc2, lds, row0, col0, stride, W0, W1, W2, WL)                                  \
    {                                                                                               \
        _Pragma("unroll")                                                                           \
        for (int dy_ = 0; dy_ < KS; dy_++) {                                                        \
            _Pragma("unroll")                                                                       \
            for (int dx_ = 0; dx_ < KS; dx_++) {                                                    \
                const f16 wt_ = WSEL(W0, W1, W2, WL, dy_ * KS + dx_);                               \
                const half2v wv_ = {wt_, wt_};                                                      \
                const f16* tp_ = (lds) + ((size_t)((row0) + dy_) * (stride) + (col0) + dx_) * CPAD; \
                half8 v0_ = *(const half8*)(tp_);                                                   \
                half8 v1_ = *(const half8*)(tp_ + 8);                                               \
                half8 v2_ = *(const half8*)(tp_ + 16);                                              \
                PK11(acc2, wv_, v0_, v1_, v2_);                                                     \
            }                                                                                       \
        }                                                                                           \
    }

// single-px conv with per-row / per-col index arrays (reflected indexing for iteration 2)
#define CONV_ACC_IDX(acc2, lds, ryArr, rxArr, stride, W0, W1, W2, WL)                               \
    {                                                                                               \
        _Pragma("unroll")                                                                           \
        for (int dy_ = 0; dy_ < KS; dy_++) {                                                        \
            _Pragma("unroll")                                                                       \
            for (int dx_ = 0; dx_ < KS; dx_++) {                                                    \
                const f16 wt_ = WSEL(W0, W1, W2, WL, dy_ * KS + dx_);                               \
                const half2v wv_ = {wt_, wt_};                                                      \
                const f16* tp_ = (lds) + ((size_t)(ryArr)[dy_] * (stride) + (rxArr)[dx_]) * CPAD;   \
                half8 v0_ = *(const half8*)(tp_);                                                   \
                half8 v1_ = *(const half8*)(tp_ + 8);                                               \
                half8 v2_ = *(const half8*)(tp_ + 16);                                              \
                PK11(acc2, wv_, v0_, v1_, v2_);                                                     \
            }                                                                                       \
        }                                                                                           \
    }

// logits: l[c] = u[c] - acc2 (promote f16 acc to f32 here)
#define LOGITS_FROM_PK(l, acc2, U0, U1, U2)                                            \
    {                                                                                  \
        _Pragma("unroll")                                                              \
        for (int j = 0; j < 10; j++) {                                                 \
            l[2 * j]     = -(float)acc2[j][0];                                         \
            l[2 * j + 1] = -(float)acc2[j][1];                                         \
        }                                                                              \
        l[20] = -(float)acc2[10][0];                                                   \
        _Pragma("unroll")                                                              \
        for (int k = 0; k < 8; k++) l[k] += (float)U0[k];                              \
        _Pragma("unroll")                                                              \
        for (int k = 0; k < 8; k++) l[8 + k] += (float)U1[k];                          \
        _Pragma("unroll")                                                              \
        for (int k = 0; k < 5; k++) l[16 + k] += (float)U2[k];                         \
    }

// logits -> softmax -> packed f16 q' triple (fully inline; no address-taken temps
// crossing a call boundary)
#define FINISH_PX(acc2, U0, U1, U2, o0, o1, o2)                                        \
    {                                                                                  \
        float l_[NCH];                                                                 \
        LOGITS_FROM_PK(l_, acc2, U0, U1, U2);                                          \
        float m_ = l_[0];                                                              \
        _Pragma("unroll")                                                              \
        for (int c = 1; c < NCH; c++) m_ = fmaxf(m_, l_[c]);                           \
        float s_ = 0.f;                                                                \
        _Pragma("unroll")                                                              \
        for (int c = 0; c < NCH; c++) { l_[c] = __expf(l_[c] - m_); s_ += l_[c]; }     \
        float is_ = 1.0f / s_;                                                         \
        _Pragma("unroll")                                                              \
        for (int k = 0; k < 8; k++) (o0)[k] = (f16)(l_[k] * is_);                      \
        _Pragma("unroll")                                                              \
        for (int k = 0; k < 8; k++) (o1)[k] = (f16)(l_[8 + k] * is_);                  \
        _Pragma("unroll")                                                              \
        for (int k = 0; k < 5; k++) (o2)[k] = (f16)(l_[16 + k] * is_);                 \
        (o2)[5] = (f16)0.f; (o2)[6] = (f16)0.f; (o2)[7] = (f16)0.f;                    \
    }

// logits -> softmax -> strided fp32 store (final iteration)
#define FINISH_PX_F32(acc2, U0, U1, U2, qo, plane)                                     \
    {                                                                                  \
        float l_[NCH];                                                                 \
        LOGITS_FROM_PK(l_, acc2, U0, U1, U2);                                          \
        float m_ = l_[0];                                                              \
        _Pragma("unroll")                                                              \
        for (int c = 1; c < NCH; c++) m_ = fmaxf(m_, l_[c]);                           \
        float s_ = 0.f;                                                                \
        _Pragma("unroll")                                                              \
        for (int c = 0; c < NCH; c++) { l_[c] = __expf(l_[c] - m_); s_ += l_[c]; }     \
        float is_ = 1.0f / s_;                                                         \
        _Pragma("unroll")                                                              \
        for (int c = 0; c < NCH; c++) (qo)[c * (plane)] = l_[c] * is_;                 \
    }

// ---------------- Kernel C: TWO fused CRF iterations, 32x32 tile, 1 px/thread ----------------
// 1024 threads (16 waves), 76.8 KB dynamic LDS -> exactly 2 blocks/CU = 32 waves/CU (max
// occupancy), grid 512 = all blocks co-resident (zero tail). Per-thread body is the PROVEN
// single-px baseline (fits the 64-VGPR cap). Pairing (R0-R3) traded TLP for LDS throughput
// and lost: the kernel is latency-bound, not LDS-throughput-bound (9 us LDS-pipe model vs
// 60 us measured). __launch_bounds__(1024,2): CUDA-style min-blocks (R2 A/B) -> cap 64,
// same as the baseline's (512,4).
template <bool FINAL>
__global__ __launch_bounds__(NTHR, 2) void crf_pair_kernel(const f16* __restrict__ qin,
                                                           const f16* __restrict__ u16,
                                                           const f16* __restrict__ wcA,
                                                           const f16* __restrict__ wcB16,
                                                           void* __restrict__ qout) {
    extern __shared__ __align__(16) f16 buf[];     // SHBYTES = 76800 B

    const int tid = threadIdx.x;          // 0..1023
    const int ix = tid & (TW - 1);        // 0..31
    const int iy = tid >> 5;              // 0..31

    // XCD band swizzle: 512 blocks; XCD (flat%8) owns 2 tile-rows per batch
    const int flat = blockIdx.x;
    const int band = flat & 7;
    const int within = flat >> 3;         // 0..63
    const int b = within >> 5;            // batch
    const int r = within & 31;
    const int x0 = (r & 15) * TW;
    const int y0 = (band * 2 + (r >> 4)) * TH;
    const int gx = x0 + ix;
    const int gy = y0 + iy;
    const size_t plane = (size_t)HH * WW;

    // ---- phase 1: async stage 40x40 q halo (4-px, for 2 iterations) ----
    const f16* qbase = qin + (size_t)b * plane * CPAD;
    f16* lbase = &buf[0];
    for (int idx = tid; idx < SCHUNK; idx += NTHR) {
        int px = idx / 3, h4 = idx - px * 3;
        int sly = px / SX, slx = px - sly * SX;
        int qy = refl(y0 - 4 + sly, HH);
        int qx = refl(x0 - 4 + slx, WW);
        const f16* g = qbase + ((size_t)(qy * WW + qx)) * CPAD + h4 * 8;
        __builtin_amdgcn_global_load_lds(
            (const __attribute__((address_space(1))) void*)g,
            (__attribute__((address_space(3))) void*)(lbase + (size_t)idx * 8),
            16, 0, 0);
    }

    // ---- inner-pixel weights + unary (registers, used by BOTH iterations) ----
    const size_t pixoff = (size_t)b * plane + (size_t)gy * WW + gx;
    const half8* wp = (const half8*)(wcA + pixoff * 24);
    half8 wa0 = wp[0], wa1 = wp[1], wa2 = wp[2];
    f16 wl = wcB16[pixoff];
    const half8* up = (const half8*)(u16 + pixoff * CPAD);
    half8 ui0 = up[0], ui1 = up[1], ui2 = up[2];

    // ---- ring pixel (threads 0..271): coords + weights + unary ----
    // ring: ext rows {0,1} (72 px), ext rows {34,35} (72 px), rows 2..33 x cols {0,1,34,35} (128 px)
    const bool has_ring = tid < RING;
    int rly = 0, rlx = 0;
    half8 wr0 = {}, wr1 = {}, wr2 = {}, ur0 = {}, ur1 = {}, ur2 = {};
    f16 wrl = (f16)0.f;
    if (has_ring) {
        int t = tid;
        if (t < 72)       { rly = t / 36;       rlx = t % 36; }
        else if (t < 144) { t -= 72;  rly = 34 + t / 36; rlx = t % 36; }
        else              { t -= 144; rly = 2 + (t >> 2); int c = t & 3; rlx = (c < 2) ? c : (c + 32); }
        int rgy = y0 + rly - 2, rgx = x0 + rlx - 2;
        int cy = min(max(rgy, 0), HH - 1);
        int cx = min(max(rgx, 0), WW - 1);
        size_t rpo = (size_t)b * plane + (size_t)cy * WW + cx;
        const half8* wpr = (const half8*)(wcA + rpo * 24);
        wr0 = wpr[0]; wr1 = wpr[1]; wr2 = wpr[2];
        wrl = wcB16[rpo];
        const half8* upr = (const half8*)(u16 + rpo * CPAD);
        ur0 = upr[0]; ur1 = upr[1]; ur2 = upr[2];
    }

    __syncthreads();   // staged q + register loads resident

    // ---- phase 2: iteration k over the extended 36x36 region ----
    half8 qr0, qr1, qr2;   // ring q'
    if (has_ring) {
        half2v acc2[11];
#pragma unroll
        for (int j = 0; j < 11; j++) acc2[j] = (half2v){(f16)0.f, (f16)0.f};
        CONV_ACC_PK(acc2, lbase, rly, rlx, SX, wr0, wr1, wr2, wrl);
        FINISH_PX(acc2, ur0, ur1, ur2, qr0, qr1, qr2);
    }

    half8 qi0, qi1, qi2;   // inner q'
    {
        half2v acc2[11];
#pragma unroll
        for (int j = 0; j < 11; j++) acc2[j] = (half2v){(f16)0.f, (f16)0.f};
        CONV_ACC_PK(acc2, lbase, iy + 2, ix + 2, SX, wa0, wa1, wa2, wl);
        FINISH_PX(acc2, ui0, ui1, ui2, qi0, qi1, qi2);
    }

    __syncthreads();   // all reads of staged q complete

    // ---- phase 3: park q' in LDS (reuse buf; layout [EPX][24], stride EX) ----
    {
        half8* d0 = (half8*)(lbase + ((size_t)(iy + 2) * EX + (ix + 2)) * CPAD);
        d0[0] = qi0; d0[1] = qi1; d0[2] = qi2;
        if (has_ring) {
            half8* e0 = (half8*)(lbase + ((size_t)rly * EX + rlx) * CPAD);
            e0[0] = qr0; e0[1] = qr1; e0[2] = qr2;
        }
    }

    __syncthreads();

    // ---- phase 4: iteration k+1 at inner pixels (w,u from registers; reflected idx) ----
    {
        int ry_[KS], rx_[KS];
#pragma unroll
        for (int d = 0; d < KS; d++) {
            ry_[d] = refl(gy + d - 2, HH) - (y0 - 2);
            rx_[d] = refl(gx + d - 2, WW) - (x0 - 2);
        }
        half2v acc2[11];
#pragma unroll
        for (int j = 0; j < 11; j++) acc2[j] = (half2v){(f16)0.f, (f16)0.f};
        CONV_ACC_IDX(acc2, lbase, ry_, rx_, EX, wa0, wa1, wa2, wl);

        if (FINAL) {
            float* qo = (float*)qout + (size_t)b * NCH * plane + (size_t)gy * WW + gx;
            FINISH_PX_F32(acc2, ui0, ui1, ui2, qo, plane);
        } else {
            half8 o0, o1, o2;
            FINISH_PX(acc2, ui0, ui1, ui2, o0, o1, o2);
            half8* qo = (half8*)((f16*)qout + pixoff * CPAD);
            qo[0] = o0; qo[1] = o1; qo[2] = o2;
        }
    }
}

extern "C" void kernel_launch(void* const* d_in, const int* in_sizes, int n_in,
                              void* d_out, int out_size, void* d_ws, size_t ws_size,
                              hipStream_t stream) {
    const float* unary = (const float*)d_in[0];   // B,21,512,512
    const float* image = (const float*)d_in[1];   // B,3,512,512
    const float* edges = (const float*)d_in[2];   // B,512,512
    float* out = (float*)d_out;                   // B,21,512,512 fp32

    const size_t plane = (size_t)HH * WW;
    char* ws = (char*)d_ws;
    f16* wcA = (f16*)ws;                                         // B*plane*24 f16 = 25.2 MB
    char* p1 = ws + sizeof(f16) * BATCH * plane * 24;
    f16* wcB16 = (f16*)p1;                                       // B*plane f16    =  1.0 MB
    char* p2 = p1 + sizeof(f16) * BATCH * plane;
    f16* u16 = (f16*)p2;                                         // 25.2 MB
    char* p3 = p2 + sizeof(f16) * BATCH * plane * CPAD;
    f16* qA = (f16*)p3;                                          // 25.2 MB
    f16* qB = qA + (size_t)BATCH * plane * CPAD;                 // 25.2 MB (total ~102 MB)

    // raise the dynamic-LDS cap once (76.8 KB > 64 KB default)
    static bool s_attr_done = false;
    if (!s_attr_done) {
        hipFuncSetAttribute((const void*)crf_pair_kernel<false>,
                            hipFuncAttributeMaxDynamicSharedMemorySize, SHBYTES);
        hipFuncSetAttribute((const void*)crf_pair_kernel<true>,
                            hipFuncAttributeMaxDynamicSharedMemorySize, SHBYTES);
        s_attr_done = true;
    }

    const int npix = BATCH * HH * WW;
    dim3 gridW(WW / TXW, HH / TYW, BATCH);
    dim3 blockW(TXW, TYW, 1);
    weights_kernel<<<gridW, blockW, 0, stream>>>(image, edges, wcA, wcB16);
    init_kernel<<<(npix + 255) / 256, 256, 0, stream>>>(unary, qA, u16);

    const int nblk = (WW / TW) * (HH / TH) * BATCH;   // 512
    f16* qa = qA;
    f16* qb = qB;
    const int npairs = NUM_ITERS / 2;                 // 5
    for (int it = 0; it < npairs - 1; it++) {
        crf_pair_kernel<false><<<nblk, NTHR, SHBYTES, stream>>>(qa, u16, wcA, wcB16, (void*)qb);
        f16* t = qa; qa = qb; qb = t;
    }
    crf_pair_kernel<true><<<nblk, NTHR, SHBYTES, stream>>>(qa, u16, wcA, wcB16, (void*)out);
}

// Round 6
// 284.895 us; speedup vs baseline: 2.0878x; 1.1472x over previous
//
#include <hip/hip_runtime.h>
#include <math.h>

#define BATCH 2
#define NCH 21
#define CPAD 24            // channels padded to 24 (48 B fp16 per pixel)
#define HH 512
#define WW 512
#define KS 5
#define RAD 2
#define NTAPS 25
#define NUM_ITERS 10

// setup-kernel tile geometry (weights part)
#define TXW 32
#define TYW 8
#define HXW (TXW + 2*RAD)   // 36
#define HYW (TYW + 2*RAD)   // 12
#define HPXW (HXW * HYW)    // 432

// fused-pair kernel geometry: 32x16 inner tile, 512 threads (PROVEN 287-us baseline)
#define TW 32
#define TH 16
#define NTHR 512
#define SX 40               // staged tile (4-px halo for 2 iters)
#define SY 24
#define SPX (SX * SY)       // 960
#define SCHUNK (SPX * 3)    // 2880 16-byte DMA chunks
#define EX 36               // extended (iter-1 output) region
#define EY 20
#define EPX (EX * EY)       // 720
#define RING (EPX - TW*TH)  // 208 ring pixels

typedef _Float16 f16;
typedef _Float16 half8 __attribute__((ext_vector_type(8)));
typedef _Float16 half2v __attribute__((ext_vector_type(2)));

__device__ __forceinline__ int refl(int i, int n) {
    if (i < 0) i = -i;
    if (i >= n) i = 2*n - 2 - i;
    return i;
}

// weight-element selector (t is a compile-time constant after unrolling)
#define WSEL(h0, h1, h2, hl, t) \
    ((t) < 8 ? (h0)[(t)] : (t) < 16 ? (h1)[(t) - 8] : (t) < 24 ? (h2)[(t) - 16] : (hl))

// ---------------- Kernel A: fused weights + init (one thread per pixel) ----------------
// weights part: TRANS/VALU-heavy (50 __expf/px). init part: HBM-heavy (21 strided fp32
// loads + 3 vector stores). Fusing lets the unary-load latency hide under the image
// staging + exp chain, and removes one launch boundary.
__global__ __launch_bounds__(256) void setup_kernel(const float* __restrict__ image,
                                                    const float* __restrict__ edges,
                                                    const float* __restrict__ unary,
                                                    f16* __restrict__ wcA,
                                                    f16* __restrict__ wcB16,
                                                    f16* __restrict__ u16,
                                                    f16* __restrict__ q) {
    __shared__ float sr_[HYW][HXW];
    __shared__ float sg_[HYW][HXW];
    __shared__ float sb_[HYW][HXW];
    __shared__ float se_[HYW][HXW];

    const int tx = threadIdx.x;
    const int ty = threadIdx.y;
    const int tid = ty * TXW + tx;
    const int x0 = blockIdx.x * TXW;
    const int y0 = blockIdx.y * TYW;
    const int b = blockIdx.z;
    const int x = x0 + tx;
    const int y = y0 + ty;
    const size_t plane = (size_t)HH * WW;
    const float* img = image + (size_t)b * 3 * plane;
    const float* edg = edges + (size_t)b * plane;

    for (int i = tid; i < HPXW; i += TXW * TYW) {
        int ly = i / HXW, lx = i - ly * HXW;
        int gy = refl(y0 + ly - RAD, HH);
        int gx = refl(x0 + lx - RAD, WW);
        int g = gy * WW + gx;
        sr_[ly][lx] = img[g];
        sg_[ly][lx] = img[plane + g];
        sb_[ly][lx] = img[2 * plane + g];
        se_[ly][lx] = edg[g];
    }

    // ---- issue init's unary loads BEFORE the barrier: latency hides under staging+exps ----
    float l[NCH];
    {
        const float* u = unary + (size_t)b * NCH * plane + (size_t)y * WW + x;
#pragma unroll
        for (int c = 0; c < NCH; c++) l[c] = u[c * plane];
    }

    __syncthreads();

    float gs[3];
    gs[0] = 1.0f; gs[1] = __expf(-1.0f / 50.0f); gs[2] = __expf(-4.0f / 50.0f);
    float gb[3];
    gb[0] = 1.0f; gb[1] = __expf(-2.0f); gb[2] = __expf(-8.0f);
    float gbs = gb[0] + 2.0f * (gb[1] + gb[2]);
    gb[0] /= gbs; gb[1] /= gbs; gb[2] /= gbs;

    const float r0 = sr_[ty + RAD][tx + RAD];
    const float g0 = sg_[ty + RAD][tx + RAD];
    const float b0 = sb_[ty + RAD][tx + RAD];
    const float e0 = se_[ty + RAD][tx + RAD];

    float wr[NTAPS], we[NTAPS];
    float sr = 0.f, se = 0.f;
#pragma unroll
    for (int dy = 0; dy < KS; dy++) {
#pragma unroll
        for (int dx = 0; dx < KS; dx++) {
            float sp = gs[abs(dy - RAD)] * gs[abs(dx - RAD)];
            float d = fabsf(sr_[ty + dy][tx + dx] - r0)
                    + fabsf(sg_[ty + dy][tx + dx] - g0)
                    + fabsf(sb_[ty + dy][tx + dx] - b0);
            float w1 = sp * __expf(-2.0f * d * d);
            float de = fabsf(se_[ty + dy][tx + dx] - e0);
            float w2 = sp * __expf(-2.0f * de * de);
            wr[dy * KS + dx] = w1;
            we[dy * KS + dx] = w2;
            sr += w1;
            se += w2;
        }
    }
    float isr = 1.0f / sr, ise = 1.0f / se;
    float wt[NTAPS];
#pragma unroll
    for (int t = 0; t < NTAPS; t++) {
        int dy = t / KS, dx = t % KS;
        float g2 = gb[abs(dy - RAD)] * gb[abs(dx - RAD)];
        wt[t] = g2 + wr[t] * isr + we[t] * ise;
    }
    const size_t pixoff = (size_t)b * plane + (size_t)y * WW + x;
    half8* wo = (half8*)(wcA + pixoff * 24);
#pragma unroll
    for (int g = 0; g < 3; g++) {
        half8 v;
#pragma unroll
        for (int k = 0; k < 8; k++) v[k] = (f16)wt[g * 8 + k];
        wo[g] = v;
    }
    wcB16[pixoff] = (f16)wt[24];

    // ---- init part: u16 store, softmax, q store (unary already in registers) ----
    {
        float m = l[0];
#pragma unroll
        for (int c = 1; c < NCH; c++) m = fmaxf(m, l[c]);

        half8* uo = (half8*)(u16 + pixoff * CPAD);
        {
            half8 v;
#pragma unroll
            for (int k = 0; k < 8; k++) v[k] = (f16)l[k];
            uo[0] = v;
#pragma unroll
            for (int k = 0; k < 8; k++) v[k] = (f16)l[8 + k];
            uo[1] = v;
#pragma unroll
            for (int k = 0; k < 5; k++) v[k] = (f16)l[16 + k];
            v[5] = (f16)0.f; v[6] = (f16)0.f; v[7] = (f16)0.f;
            uo[2] = v;
        }

        float e[NCH];
        float s = 0.f;
#pragma unroll
        for (int c = 0; c < NCH; c++) { e[c] = __expf(l[c] - m); s += e[c]; }
        float is = 1.0f / s;
        half8* qo = (half8*)(q + pixoff * CPAD);
        {
            half8 v;
#pragma unroll
            for (int k = 0; k < 8; k++) v[k] = (f16)(e[k] * is);
            qo[0] = v;
#pragma unroll
            for (int k = 0; k < 8; k++) v[k] = (f16)(e[8 + k] * is);
            qo[1] = v;
#pragma unroll
            for (int k = 0; k < 5; k++) v[k] = (f16)(e[16 + k] * is);
            v[5] = (f16)0.f; v[6] = (f16)0.f; v[7] = (f16)0.f;
            qo[2] = v;
        }
    }
}

// packed-f16 conv helper: 25-tap gather, v_pk_fma_f16 (11 packed MACs per tap)
#define CONV_ACC_PK(acc2, lds, row0, col0, stride, W0, W1, W2, WL)                     \
    {                                                                                  \
        _Pragma("unroll")                                                              \
        for (int dy = 0; dy < KS; dy++) {                                              \
            _Pragma("unroll")                                                          \
            for (int dx = 0; dx < KS; dx++) {                                          \
                const f16 wt_ = WSEL(W0, W1, W2, WL, dy * KS + dx);                    \
                const half2v wv_ = {wt_, wt_};                                         \
                const f16* tp = (lds) + ((size_t)((row0) + dy) * (stride) + (col0) + dx) * CPAD; \
                half8 v0 = *(const half8*)(tp);                                        \
                half8 v1 = *(const half8*)(tp + 8);                                    \
                half8 v2 = *(const half8*)(tp + 16);                                   \
                acc2[0]  = __builtin_elementwise_fma(wv_, __builtin_shufflevector(v0, v0, 0, 1), acc2[0]);  \
                acc2[1]  = __builtin_elementwise_fma(wv_, __builtin_shufflevector(v0, v0, 2, 3), acc2[1]);  \
                acc2[2]  = __builtin_elementwise_fma(wv_, __builtin_shufflevector(v0, v0, 4, 5), acc2[2]);  \
                acc2[3]  = __builtin_elementwise_fma(wv_, __builtin_shufflevector(v0, v0, 6, 7), acc2[3]);  \
                acc2[4]  = __builtin_elementwise_fma(wv_, __builtin_shufflevector(v1, v1, 0, 1), acc2[4]);  \
                acc2[5]  = __builtin_elementwise_fma(wv_, __builtin_shufflevector(v1, v1, 2, 3), acc2[5]);  \
                acc2[6]  = __builtin_elementwise_fma(wv_, __builtin_shufflevector(v1, v1, 4, 5), acc2[6]);  \
                acc2[7]  = __builtin_elementwise_fma(wv_, __builtin_shufflevector(v1, v1, 6, 7), acc2[7]);  \
                acc2[8]  = __builtin_elementwise_fma(wv_, __builtin_shufflevector(v2, v2, 0, 1), acc2[8]);  \
                acc2[9]  = __builtin_elementwise_fma(wv_, __builtin_shufflevector(v2, v2, 2, 3), acc2[9]);  \
                acc2[10] = __builtin_elementwise_fma(wv_, __builtin_shufflevector(v2, v2, 4, 5), acc2[10]); \
            }                                                                          \
        }                                                                              \
    }

// logits: l[c] = u[c] - acc2 (promote f16 acc to f32 here)
#define LOGITS_FROM_PK(l, acc2, U0, U1, U2)                                            \
    {                                                                                  \
        _Pragma("unroll")                                                              \
        for (int j = 0; j < 10; j++) {                                                 \
            l[2 * j]     = -(float)acc2[j][0];                                         \
            l[2 * j + 1] = -(float)acc2[j][1];                                         \
        }                                                                              \
        l[20] = -(float)acc2[10][0];                                                   \
        _Pragma("unroll")                                                              \
        for (int k = 0; k < 8; k++) l[k] += (float)U0[k];                              \
        _Pragma("unroll")                                                              \
        for (int k = 0; k < 8; k++) l[8 + k] += (float)U1[k];                          \
        _Pragma("unroll")                                                              \
        for (int k = 0; k < 5; k++) l[16 + k] += (float)U2[k];                         \
    }

// ---------------- Kernel C: TWO fused CRF iterations per launch (PROVEN 287-us body) ----
template <bool FINAL>
__global__ __launch_bounds__(NTHR, 4) void crf_pair_kernel(const f16* __restrict__ qin,
                                                           const f16* __restrict__ u16,
                                                           const f16* __restrict__ wcA,
                                                           const f16* __restrict__ wcB16,
                                                           void* __restrict__ qout) {
    __shared__ __align__(16) f16 buf[SPX][CPAD];   // 46080 B; staged q, then reused for q'

    const int tid = threadIdx.x;          // 0..511
    const int ix = tid & (TW - 1);        // 0..31
    const int iy = tid >> 5;              // 0..15

    // XCD band swizzle: 1024 blocks; XCD (flat%8) owns 4 tile-rows per batch
    const int flat = blockIdx.x;
    const int band = flat & 7;
    const int within = flat >> 3;         // 0..127
    const int b = within >> 6;
    const int r = within & 63;
    const int x0 = (r & 15) * TW;
    const int y0 = (band * 4 + (r >> 4)) * TH;
    const int gx = x0 + ix;
    const int gy = y0 + iy;
    const size_t plane = (size_t)HH * WW;

    // ---- phase 1: async stage 24x40 q halo (4-px, for 2 iterations) ----
    const f16* qbase = qin + (size_t)b * plane * CPAD;
    f16* lbase = &buf[0][0];
    for (int idx = tid; idx < SCHUNK; idx += NTHR) {
        int px = idx / 3, h4 = idx - px * 3;
        int sly = px / SX, slx = px - sly * SX;
        int qy = refl(y0 - 4 + sly, HH);
        int qx = refl(x0 - 4 + slx, WW);
        const f16* g = qbase + ((size_t)(qy * WW + qx)) * CPAD + h4 * 8;
        __builtin_amdgcn_global_load_lds(
            (const __attribute__((address_space(1))) void*)g,
            (__attribute__((address_space(3))) void*)(lbase + (size_t)idx * 8),
            16, 0, 0);
    }

    // ---- fetch inner-pixel weights + unary (registers, used by BOTH iterations) ----
    const size_t pixoff = (size_t)b * plane + (size_t)gy * WW + gx;
    const half8* wp = (const half8*)(wcA + pixoff * 24);
    half8 wa0 = wp[0], wa1 = wp[1], wa2 = wp[2];
    f16 wl = wcB16[pixoff];
    const half8* up = (const half8*)(u16 + pixoff * CPAD);
    half8 ui0 = up[0], ui1 = up[1], ui2 = up[2];

    // ---- ring pixel (threads 0..207): coords + weights + unary ----
    const bool has_ring = tid < RING;
    int rly = 0, rlx = 0;
    half8 wr0 = {}, wr1 = {}, wr2 = {}, ur0 = {}, ur1 = {}, ur2 = {};
    f16 wrl = (f16)0.f;
    if (has_ring) {
        int t = tid;
        if (t < 72)       { rly = t / 36;       rlx = t % 36; }
        else if (t < 144) { t -= 72;  rly = 18 + t / 36; rlx = t % 36; }
        else              { t -= 144; rly = 2 + (t >> 2); int c = t & 3; rlx = (c < 2) ? c : (c + 32); }
        int rgy = y0 + rly - 2, rgx = x0 + rlx - 2;
        int cy = min(max(rgy, 0), HH - 1);
        int cx = min(max(rgx, 0), WW - 1);
        size_t rpo = (size_t)b * plane + (size_t)cy * WW + cx;
        const half8* wpr = (const half8*)(wcA + rpo * 24);
        wr0 = wpr[0]; wr1 = wpr[1]; wr2 = wpr[2];
        wrl = wcB16[rpo];
        const half8* upr = (const half8*)(u16 + rpo * CPAD);
        ur0 = upr[0]; ur1 = upr[1]; ur2 = upr[2];
    }

    __syncthreads();   // staged q + register loads resident

    // ---- phase 2: iteration k over the extended 36x20 region (packed f16 MACs) ----
    half8 qr0, qr1, qr2;   // ring q' (packed f16)
    if (has_ring) {
        half2v acc2[11];
#pragma unroll
        for (int j = 0; j < 11; j++) acc2[j] = (half2v){(f16)0.f, (f16)0.f};
        CONV_ACC_PK(acc2, lbase, rly, rlx, SX, wr0, wr1, wr2, wrl);
        float l[NCH];
        LOGITS_FROM_PK(l, acc2, ur0, ur1, ur2);
        float m = l[0];
#pragma unroll
        for (int c = 1; c < NCH; c++) m = fmaxf(m, l[c]);
        float s = 0.f;
#pragma unroll
        for (int c = 0; c < NCH; c++) { l[c] = __expf(l[c] - m); s += l[c]; }
        float is = 1.0f / s;
#pragma unroll
        for (int k = 0; k < 8; k++) qr0[k] = (f16)(l[k] * is);
#pragma unroll
        for (int k = 0; k < 8; k++) qr1[k] = (f16)(l[8 + k] * is);
#pragma unroll
        for (int k = 0; k < 5; k++) qr2[k] = (f16)(l[16 + k] * is);
        qr2[5] = (f16)0.f; qr2[6] = (f16)0.f; qr2[7] = (f16)0.f;
    }

    half8 qi0, qi1, qi2;   // inner q' (packed f16)
    {
        half2v acc2[11];
#pragma unroll
        for (int j = 0; j < 11; j++) acc2[j] = (half2v){(f16)0.f, (f16)0.f};
        CONV_ACC_PK(acc2, lbase, iy + 2, ix + 2, SX, wa0, wa1, wa2, wl);
        float l[NCH];
        LOGITS_FROM_PK(l, acc2, ui0, ui1, ui2);
        float m = l[0];
#pragma unroll
        for (int c = 1; c < NCH; c++) m = fmaxf(m, l[c]);
        float s = 0.f;
#pragma unroll
        for (int c = 0; c < NCH; c++) { l[c] = __expf(l[c] - m); s += l[c]; }
        float is = 1.0f / s;
#pragma unroll
        for (int k = 0; k < 8; k++) qi0[k] = (f16)(l[k] * is);
#pragma unroll
        for (int k = 0; k < 8; k++) qi1[k] = (f16)(l[8 + k] * is);
#pragma unroll
        for (int k = 0; k < 5; k++) qi2[k] = (f16)(l[16 + k] * is);
        qi2[5] = (f16)0.f; qi2[6] = (f16)0.f; qi2[7] = (f16)0.f;
    }

    __syncthreads();   // all reads of staged q complete

    // ---- phase 3: park q' in LDS (reuse buf; layout [EPX][24], stride EX) ----
    {
        half8* d = (half8*)(lbase + ((size_t)(iy + 2) * EX + (ix + 2)) * CPAD);
        d[0] = qi0; d[1] = qi1; d[2] = qi2;
        if (has_ring) {
            half8* dr = (half8*)(lbase + ((size_t)rly * EX + rlx) * CPAD);
            dr[0] = qr0; dr[1] = qr1; dr[2] = qr2;
        }
    }

    __syncthreads();

    // ---- phase 4: iteration k+1 at inner pixels (w,u from registers) ----
    {
        int ry[KS], rx[KS];
#pragma unroll
        for (int d = 0; d < KS; d++) {
            ry[d] = refl(gy + d - 2, HH) - (y0 - 2);
            rx[d] = refl(gx + d - 2, WW) - (x0 - 2);
        }
        half2v acc2[11];
#pragma unroll
        for (int j = 0; j < 11; j++) acc2[j] = (half2v){(f16)0.f, (f16)0.f};
#pragma unroll
        for (int dy = 0; dy < KS; dy++) {
#pragma unroll
            for (int dx = 0; dx < KS; dx++) {
                const f16 wt_ = WSEL(wa0, wa1, wa2, wl, dy * KS + dx);
                const half2v wv_ = {wt_, wt_};
                const f16* tp = lbase + ((size_t)ry[dy] * EX + rx[dx]) * CPAD;
                half8 v0 = *(const half8*)(tp);
                half8 v1 = *(const half8*)(tp + 8);
                half8 v2 = *(const half8*)(tp + 16);
                acc2[0]  = __builtin_elementwise_fma(wv_, __builtin_shufflevector(v0, v0, 0, 1), acc2[0]);
                acc2[1]  = __builtin_elementwise_fma(wv_, __builtin_shufflevector(v0, v0, 2, 3), acc2[1]);
                acc2[2]  = __builtin_elementwise_fma(wv_, __builtin_shufflevector(v0, v0, 4, 5), acc2[2]);
                acc2[3]  = __builtin_elementwise_fma(wv_, __builtin_shufflevector(v0, v0, 6, 7), acc2[3]);
                acc2[4]  = __builtin_elementwise_fma(wv_, __builtin_shufflevector(v1, v1, 0, 1), acc2[4]);
                acc2[5]  = __builtin_elementwise_fma(wv_, __builtin_shufflevector(v1, v1, 2, 3), acc2[5]);
                acc2[6]  = __builtin_elementwise_fma(wv_, __builtin_shufflevector(v1, v1, 4, 5), acc2[6]);
                acc2[7]  = __builtin_elementwise_fma(wv_, __builtin_shufflevector(v1, v1, 6, 7), acc2[7]);
                acc2[8]  = __builtin_elementwise_fma(wv_, __builtin_shufflevector(v2, v2, 0, 1), acc2[8]);
                acc2[9]  = __builtin_elementwise_fma(wv_, __builtin_shufflevector(v2, v2, 2, 3), acc2[9]);
                acc2[10] = __builtin_elementwise_fma(wv_, __builtin_shufflevector(v2, v2, 4, 5), acc2[10]);
            }
        }
        float l[NCH];
        LOGITS_FROM_PK(l, acc2, ui0, ui1, ui2);
        float m = l[0];
#pragma unroll
        for (int c = 1; c < NCH; c++) m = fmaxf(m, l[c]);
        float s = 0.f;
#pragma unroll
        for (int c = 0; c < NCH; c++) { l[c] = __expf(l[c] - m); s += l[c]; }
        float is = 1.0f / s;

        if (FINAL) {
            float* qo = (float*)qout + (size_t)b * NCH * plane + (size_t)gy * WW + gx;
#pragma unroll
            for (int c = 0; c < NCH; c++) qo[c * plane] = l[c] * is;
        } else {
            half8* qo = (half8*)((f16*)qout + pixoff * CPAD);
            half8 o0, o1, o2;
#pragma unroll
            for (int k = 0; k < 8; k++) o0[k] = (f16)(l[k] * is);
#pragma unroll
            for (int k = 0; k < 8; k++) o1[k] = (f16)(l[8 + k] * is);
#pragma unroll
            for (int k = 0; k < 5; k++) o2[k] = (f16)(l[16 + k] * is);
            o2[5] = (f16)0.f; o2[6] = (f16)0.f; o2[7] = (f16)0.f;
            qo[0] = o0; qo[1] = o1; qo[2] = o2;
        }
    }
}

extern "C" void kernel_launch(void* const* d_in, const int* in_sizes, int n_in,
                              void* d_out, int out_size, void* d_ws, size_t ws_size,
                              hipStream_t stream) {
    const float* unary = (const float*)d_in[0];   // B,21,512,512
    const float* image = (const float*)d_in[1];   // B,3,512,512
    const float* edges = (const float*)d_in[2];   // B,512,512
    float* out = (float*)d_out;                   // B,21,512,512 fp32

    const size_t plane = (size_t)HH * WW;
    char* ws = (char*)d_ws;
    f16* wcA = (f16*)ws;                                         // B*plane*24 f16 = 25.2 MB
    char* p1 = ws + sizeof(f16) * BATCH * plane * 24;
    f16* wcB16 = (f16*)p1;                                       // B*plane f16    =  1.0 MB
    char* p2 = p1 + sizeof(f16) * BATCH * plane;
    f16* u16 = (f16*)p2;                                         // 25.2 MB
    char* p3 = p2 + sizeof(f16) * BATCH * plane * CPAD;
    f16* qA = (f16*)p3;                                          // 25.2 MB
    f16* qB = qA + (size_t)BATCH * plane * CPAD;                 // 25.2 MB (total ~102 MB)

    dim3 gridW(WW / TXW, HH / TYW, BATCH);
    dim3 blockW(TXW, TYW, 1);
    setup_kernel<<<gridW, blockW, 0, stream>>>(image, edges, unary, wcA, wcB16, u16, qA);

    const int nblk = (WW / TW) * (HH / TH) * BATCH;   // 1024
    f16* qa = qA;
    f16* qb = qB;
    const int npairs = NUM_ITERS / 2;                 // 5
    for (int it = 0; it < npairs - 1; it++) {
        crf_pair_kernel<false><<<nblk, NTHR, 0, stream>>>(qa, u16, wcA, wcB16, (void*)qb);
        f16* t = qa; qa = qb; qb = t;
    }
    crf_pair_kernel<true><<<nblk, NTHR, 0, stream>>>(qa, u16, wcA, wcB16, (void*)out);
}

// Round 7
// 283.702 us; speedup vs baseline: 2.0965x; 1.0042x over previous
//
#include <hip/hip_runtime.h>
#include <math.h>

#define BATCH 2
#define NCH 21
#define CPAD 24            // channels padded to 24 (48 B fp16 per pixel)
#define WUPAD 48           // packed per-pixel w(24) + u(21) + w24 + pad = 48 halfs (96 B)
#define HH 512
#define WW 512
#define KS 5
#define RAD 2
#define NTAPS 25
#define NUM_ITERS 10

// setup-kernel tile geometry (weights part): 32x16, 512 threads
#define TXW 32
#define TYW 16
#define HXW (TXW + 2*RAD)   // 36
#define HYW (TYW + 2*RAD)   // 20
#define HPXW (HXW * HYW)    // 720

// fused-pair kernel geometry: 32x16 inner tile, 512 threads (PROVEN 287-us baseline)
#define TW 32
#define TH 16
#define NTHR 512
#define SX 40               // staged tile (4-px halo for 2 iters)
#define SY 24
#define SPX (SX * SY)       // 960
#define SCHUNK (SPX * 3)    // 2880 16-byte DMA chunks
#define EX 36               // extended (iter-1 output) region
#define EY 20
#define EPX (EX * EY)       // 720
#define RING (EPX - TW*TH)  // 208 ring pixels

typedef _Float16 f16;
typedef _Float16 half8 __attribute__((ext_vector_type(8)));
typedef _Float16 half2v __attribute__((ext_vector_type(2)));

__device__ __forceinline__ int refl(int i, int n) {
    if (i < 0) i = -i;
    if (i >= n) i = 2*n - 2 - i;
    return i;
}

// weight-element selector (t is a compile-time constant after unrolling)
#define WSEL(h0, h1, h2, hl, t) \
    ((t) < 8 ? (h0)[(t)] : (t) < 16 ? (h1)[(t) - 8] : (t) < 24 ? (h2)[(t) - 16] : (hl))

// ---------------- Kernel A: fused weights + init (one thread per pixel) ----------------
// Writes the packed per-pixel record wu[px][48]: [0:24)=w0..w23, [24:45)=u0..u20,
// [45]=w24, [46:48)=pad. One contiguous 96-B stream replaces three separate streams.
__global__ __launch_bounds__(512) void setup_kernel(const float* __restrict__ image,
                                                    const float* __restrict__ edges,
                                                    const float* __restrict__ unary,
                                                    f16* __restrict__ wu,
                                                    f16* __restrict__ q) {
    __shared__ float sr_[HYW][HXW];
    __shared__ float sg_[HYW][HXW];
    __shared__ float sb_[HYW][HXW];
    __shared__ float se_[HYW][HXW];

    const int tx = threadIdx.x;
    const int ty = threadIdx.y;
    const int tid = ty * TXW + tx;
    const int x0 = blockIdx.x * TXW;
    const int y0 = blockIdx.y * TYW;
    const int b = blockIdx.z;
    const int x = x0 + tx;
    const int y = y0 + ty;
    const size_t plane = (size_t)HH * WW;
    const float* img = image + (size_t)b * 3 * plane;
    const float* edg = edges + (size_t)b * plane;

    for (int i = tid; i < HPXW; i += TXW * TYW) {
        int ly = i / HXW, lx = i - ly * HXW;
        int gy = refl(y0 + ly - RAD, HH);
        int gx = refl(x0 + lx - RAD, WW);
        int g = gy * WW + gx;
        sr_[ly][lx] = img[g];
        sg_[ly][lx] = img[plane + g];
        sb_[ly][lx] = img[2 * plane + g];
        se_[ly][lx] = edg[g];
    }

    // ---- issue init's unary loads BEFORE the barrier: latency hides under staging ----
    float l[NCH];
    {
        const float* u = unary + (size_t)b * NCH * plane + (size_t)y * WW + x;
#pragma unroll
        for (int c = 0; c < NCH; c++) l[c] = u[c * plane];
    }

    __syncthreads();

    float gs[3];
    gs[0] = 1.0f; gs[1] = __expf(-1.0f / 50.0f); gs[2] = __expf(-4.0f / 50.0f);
    float gb[3];
    gb[0] = 1.0f; gb[1] = __expf(-2.0f); gb[2] = __expf(-8.0f);
    float gbs = gb[0] + 2.0f * (gb[1] + gb[2]);
    gb[0] /= gbs; gb[1] /= gbs; gb[2] /= gbs;

    const float r0 = sr_[ty + RAD][tx + RAD];
    const float g0 = sg_[ty + RAD][tx + RAD];
    const float b0 = sb_[ty + RAD][tx + RAD];
    const float e0 = se_[ty + RAD][tx + RAD];

    float wr[NTAPS], we[NTAPS];
    float sr = 0.f, se = 0.f;
#pragma unroll
    for (int dy = 0; dy < KS; dy++) {
#pragma unroll
        for (int dx = 0; dx < KS; dx++) {
            float sp = gs[abs(dy - RAD)] * gs[abs(dx - RAD)];
            float d = fabsf(sr_[ty + dy][tx + dx] - r0)
                    + fabsf(sg_[ty + dy][tx + dx] - g0)
                    + fabsf(sb_[ty + dy][tx + dx] - b0);
            float w1 = sp * __expf(-2.0f * d * d);
            float de = fabsf(se_[ty + dy][tx + dx] - e0);
            float w2 = sp * __expf(-2.0f * de * de);
            wr[dy * KS + dx] = w1;
            we[dy * KS + dx] = w2;
            sr += w1;
            se += w2;
        }
    }
    float isr = 1.0f / sr, ise = 1.0f / se;
    float wt[NTAPS];
#pragma unroll
    for (int t = 0; t < NTAPS; t++) {
        int dy = t / KS, dx = t % KS;
        float g2 = gb[abs(dy - RAD)] * gb[abs(dx - RAD)];
        wt[t] = g2 + wr[t] * isr + we[t] * ise;
    }
    const size_t pixoff = (size_t)b * plane + (size_t)y * WW + x;

    // ---- packed wu record: 6 contiguous half8 stores ----
    {
        half8* wo = (half8*)(wu + pixoff * WUPAD);
        half8 v;
#pragma unroll
        for (int k = 0; k < 8; k++) v[k] = (f16)wt[k];
        wo[0] = v;
#pragma unroll
        for (int k = 0; k < 8; k++) v[k] = (f16)wt[8 + k];
        wo[1] = v;
#pragma unroll
        for (int k = 0; k < 8; k++) v[k] = (f16)wt[16 + k];
        wo[2] = v;
#pragma unroll
        for (int k = 0; k < 8; k++) v[k] = (f16)l[k];
        wo[3] = v;
#pragma unroll
        for (int k = 0; k < 8; k++) v[k] = (f16)l[8 + k];
        wo[4] = v;
#pragma unroll
        for (int k = 0; k < 5; k++) v[k] = (f16)l[16 + k];
        v[5] = (f16)wt[24];
        v[6] = (f16)0.f; v[7] = (f16)0.f;
        wo[5] = v;
    }

    // ---- init softmax -> q ----
    {
        float m = l[0];
#pragma unroll
        for (int c = 1; c < NCH; c++) m = fmaxf(m, l[c]);
        float e[NCH];
        float s = 0.f;
#pragma unroll
        for (int c = 0; c < NCH; c++) { e[c] = __expf(l[c] - m); s += e[c]; }
        float is = 1.0f / s;
        half8* qo = (half8*)(q + pixoff * CPAD);
        half8 v;
#pragma unroll
        for (int k = 0; k < 8; k++) v[k] = (f16)(e[k] * is);
        qo[0] = v;
#pragma unroll
        for (int k = 0; k < 8; k++) v[k] = (f16)(e[8 + k] * is);
        qo[1] = v;
#pragma unroll
        for (int k = 0; k < 5; k++) v[k] = (f16)(e[16 + k] * is);
        v[5] = (f16)0.f; v[6] = (f16)0.f; v[7] = (f16)0.f;
        qo[2] = v;
    }
}

// packed-f16 conv helper: 25-tap gather, v_pk_fma_f16 (11 packed MACs per tap)
#define CONV_ACC_PK(acc2, lds, row0, col0, stride, W0, W1, W2, WL)                     \
    {                                                                                  \
        _Pragma("unroll")                                                              \
        for (int dy = 0; dy < KS; dy++) {                                              \
            _Pragma("unroll")                                                          \
            for (int dx = 0; dx < KS; dx++) {                                          \
                const f16 wt_ = WSEL(W0, W1, W2, WL, dy * KS + dx);                    \
                const half2v wv_ = {wt_, wt_};                                         \
                const f16* tp = (lds) + ((size_t)((row0) + dy) * (stride) + (col0) + dx) * CPAD; \
                half8 v0 = *(const half8*)(tp);                                        \
                half8 v1 = *(const half8*)(tp + 8);                                    \
                half8 v2 = *(const half8*)(tp + 16);                                   \
                acc2[0]  = __builtin_elementwise_fma(wv_, __builtin_shufflevector(v0, v0, 0, 1), acc2[0]);  \
                acc2[1]  = __builtin_elementwise_fma(wv_, __builtin_shufflevector(v0, v0, 2, 3), acc2[1]);  \
                acc2[2]  = __builtin_elementwise_fma(wv_, __builtin_shufflevector(v0, v0, 4, 5), acc2[2]);  \
                acc2[3]  = __builtin_elementwise_fma(wv_, __builtin_shufflevector(v0, v0, 6, 7), acc2[3]);  \
                acc2[4]  = __builtin_elementwise_fma(wv_, __builtin_shufflevector(v1, v1, 0, 1), acc2[4]);  \
                acc2[5]  = __builtin_elementwise_fma(wv_, __builtin_shufflevector(v1, v1, 2, 3), acc2[5]);  \
                acc2[6]  = __builtin_elementwise_fma(wv_, __builtin_shufflevector(v1, v1, 4, 5), acc2[6]);  \
                acc2[7]  = __builtin_elementwise_fma(wv_, __builtin_shufflevector(v1, v1, 6, 7), acc2[7]);  \
                acc2[8]  = __builtin_elementwise_fma(wv_, __builtin_shufflevector(v2, v2, 0, 1), acc2[8]);  \
                acc2[9]  = __builtin_elementwise_fma(wv_, __builtin_shufflevector(v2, v2, 2, 3), acc2[9]);  \
                acc2[10] = __builtin_elementwise_fma(wv_, __builtin_shufflevector(v2, v2, 4, 5), acc2[10]); \
            }                                                                          \
        }                                                                              \
    }

// logits: l[c] = u[c] - acc2 (promote f16 acc to f32 here)
#define LOGITS_FROM_PK(l, acc2, U0, U1, U2)                                            \
    {                                                                                  \
        _Pragma("unroll")                                                              \
        for (int j = 0; j < 10; j++) {                                                 \
            l[2 * j]     = -(float)acc2[j][0];                                         \
            l[2 * j + 1] = -(float)acc2[j][1];                                         \
        }                                                                              \
        l[20] = -(float)acc2[10][0];                                                   \
        _Pragma("unroll")                                                              \
        for (int k = 0; k < 8; k++) l[k] += (float)U0[k];                              \
        _Pragma("unroll")                                                              \
        for (int k = 0; k < 8; k++) l[8 + k] += (float)U1[k];                          \
        _Pragma("unroll")                                                              \
        for (int k = 0; k < 5; k++) l[16 + k] += (float)U2[k];                         \
    }

// ---------------- Kernel C: TWO fused CRF iterations per launch (PROVEN 287-us body) ----
// Only change vs R5: w,u read from the packed wu stream (6 contiguous half8, wl = U2[5]).
template <bool FINAL>
__global__ __launch_bounds__(NTHR, 4) void crf_pair_kernel(const f16* __restrict__ qin,
                                                           const f16* __restrict__ wu,
                                                           void* __restrict__ qout) {
    __shared__ __align__(16) f16 buf[SPX][CPAD];   // 46080 B; staged q, then reused for q'

    const int tid = threadIdx.x;          // 0..511
    const int ix = tid & (TW - 1);        // 0..31
    const int iy = tid >> 5;              // 0..15

    // XCD band swizzle: 1024 blocks; XCD (flat%8) owns 4 tile-rows per batch
    const int flat = blockIdx.x;
    const int band = flat & 7;
    const int within = flat >> 3;         // 0..127
    const int b = within >> 6;
    const int r = within & 63;
    const int x0 = (r & 15) * TW;
    const int y0 = (band * 4 + (r >> 4)) * TH;
    const int gx = x0 + ix;
    const int gy = y0 + iy;
    const size_t plane = (size_t)HH * WW;

    // ---- phase 1: async stage 24x40 q halo (4-px, for 2 iterations) ----
    const f16* qbase = qin + (size_t)b * plane * CPAD;
    f16* lbase = &buf[0][0];
    for (int idx = tid; idx < SCHUNK; idx += NTHR) {
        int px = idx / 3, h4 = idx - px * 3;
        int sly = px / SX, slx = px - sly * SX;
        int qy = refl(y0 - 4 + sly, HH);
        int qx = refl(x0 - 4 + slx, WW);
        const f16* g = qbase + ((size_t)(qy * WW + qx)) * CPAD + h4 * 8;
        __builtin_amdgcn_global_load_lds(
            (const __attribute__((address_space(1))) void*)g,
            (__attribute__((address_space(3))) void*)(lbase + (size_t)idx * 8),
            16, 0, 0);
    }

    // ---- fetch inner-pixel packed w+u (registers, used by BOTH iterations) ----
    const size_t pixoff = (size_t)b * plane + (size_t)gy * WW + gx;
    const half8* wp = (const half8*)(wu + pixoff * WUPAD);
    half8 wa0 = wp[0], wa1 = wp[1], wa2 = wp[2];
    half8 ui0 = wp[3], ui1 = wp[4], ui2 = wp[5];
    f16 wl = ui2[5];

    // ---- ring pixel (threads 0..207): coords + packed w+u ----
    const bool has_ring = tid < RING;
    int rly = 0, rlx = 0;
    half8 wr0 = {}, wr1 = {}, wr2 = {}, ur0 = {}, ur1 = {}, ur2 = {};
    f16 wrl = (f16)0.f;
    if (has_ring) {
        int t = tid;
        if (t < 72)       { rly = t / 36;       rlx = t % 36; }
        else if (t < 144) { t -= 72;  rly = 18 + t / 36; rlx = t % 36; }
        else              { t -= 144; rly = 2 + (t >> 2); int c = t & 3; rlx = (c < 2) ? c : (c + 32); }
        int rgy = y0 + rly - 2, rgx = x0 + rlx - 2;
        int cy = min(max(rgy, 0), HH - 1);
        int cx = min(max(rgx, 0), WW - 1);
        size_t rpo = (size_t)b * plane + (size_t)cy * WW + cx;
        const half8* wpr = (const half8*)(wu + rpo * WUPAD);
        wr0 = wpr[0]; wr1 = wpr[1]; wr2 = wpr[2];
        ur0 = wpr[3]; ur1 = wpr[4]; ur2 = wpr[5];
        wrl = ur2[5];
    }

    __syncthreads();   // staged q + register loads resident

    // ---- phase 2: iteration k over the extended 36x20 region (packed f16 MACs) ----
    half8 qr0, qr1, qr2;   // ring q' (packed f16)
    if (has_ring) {
        half2v acc2[11];
#pragma unroll
        for (int j = 0; j < 11; j++) acc2[j] = (half2v){(f16)0.f, (f16)0.f};
        CONV_ACC_PK(acc2, lbase, rly, rlx, SX, wr0, wr1, wr2, wrl);
        float l[NCH];
        LOGITS_FROM_PK(l, acc2, ur0, ur1, ur2);
        float m = l[0];
#pragma unroll
        for (int c = 1; c < NCH; c++) m = fmaxf(m, l[c]);
        float s = 0.f;
#pragma unroll
        for (int c = 0; c < NCH; c++) { l[c] = __expf(l[c] - m); s += l[c]; }
        float is = 1.0f / s;
#pragma unroll
        for (int k = 0; k < 8; k++) qr0[k] = (f16)(l[k] * is);
#pragma unroll
        for (int k = 0; k < 8; k++) qr1[k] = (f16)(l[8 + k] * is);
#pragma unroll
        for (int k = 0; k < 5; k++) qr2[k] = (f16)(l[16 + k] * is);
        qr2[5] = (f16)0.f; qr2[6] = (f16)0.f; qr2[7] = (f16)0.f;
    }

    half8 qi0, qi1, qi2;   // inner q' (packed f16)
    {
        half2v acc2[11];
#pragma unroll
        for (int j = 0; j < 11; j++) acc2[j] = (half2v){(f16)0.f, (f16)0.f};
        CONV_ACC_PK(acc2, lbase, iy + 2, ix + 2, SX, wa0, wa1, wa2, wl);
        float l[NCH];
        LOGITS_FROM_PK(l, acc2, ui0, ui1, ui2);
        float m = l[0];
#pragma unroll
        for (int c = 1; c < NCH; c++) m = fmaxf(m, l[c]);
        float s = 0.f;
#pragma unroll
        for (int c = 0; c < NCH; c++) { l[c] = __expf(l[c] - m); s += l[c]; }
        float is = 1.0f / s;
#pragma unroll
        for (int k = 0; k < 8; k++) qi0[k] = (f16)(l[k] * is);
#pragma unroll
        for (int k = 0; k < 8; k++) qi1[k] = (f16)(l[8 + k] * is);
#pragma unroll
        for (int k = 0; k < 5; k++) qi2[k] = (f16)(l[16 + k] * is);
        qi2[5] = (f16)0.f; qi2[6] = (f16)0.f; qi2[7] = (f16)0.f;
    }

    __syncthreads();   // all reads of staged q complete

    // ---- phase 3: park q' in LDS (reuse buf; layout [EPX][24], stride EX) ----
    {
        half8* d = (half8*)(lbase + ((size_t)(iy + 2) * EX + (ix + 2)) * CPAD);
        d[0] = qi0; d[1] = qi1; d[2] = qi2;
        if (has_ring) {
            half8* dr = (half8*)(lbase + ((size_t)rly * EX + rlx) * CPAD);
            dr[0] = qr0; dr[1] = qr1; dr[2] = qr2;
        }
    }

    __syncthreads();

    // ---- phase 4: iteration k+1 at inner pixels (w,u from registers) ----
    {
        int ry[KS], rx[KS];
#pragma unroll
        for (int d = 0; d < KS; d++) {
            ry[d] = refl(gy + d - 2, HH) - (y0 - 2);
            rx[d] = refl(gx + d - 2, WW) - (x0 - 2);
        }
        half2v acc2[11];
#pragma unroll
        for (int j = 0; j < 11; j++) acc2[j] = (half2v){(f16)0.f, (f16)0.f};
#pragma unroll
        for (int dy = 0; dy < KS; dy++) {
#pragma unroll
            for (int dx = 0; dx < KS; dx++) {
                const f16 wt_ = WSEL(wa0, wa1, wa2, wl, dy * KS + dx);
                const half2v wv_ = {wt_, wt_};
                const f16* tp = lbase + ((size_t)ry[dy] * EX + rx[dx]) * CPAD;
                half8 v0 = *(const half8*)(tp);
                half8 v1 = *(const half8*)(tp + 8);
                half8 v2 = *(const half8*)(tp + 16);
                acc2[0]  = __builtin_elementwise_fma(wv_, __builtin_shufflevector(v0, v0, 0, 1), acc2[0]);
                acc2[1]  = __builtin_elementwise_fma(wv_, __builtin_shufflevector(v0, v0, 2, 3), acc2[1]);
                acc2[2]  = __builtin_elementwise_fma(wv_, __builtin_shufflevector(v0, v0, 4, 5), acc2[2]);
                acc2[3]  = __builtin_elementwise_fma(wv_, __builtin_shufflevector(v0, v0, 6, 7), acc2[3]);
                acc2[4]  = __builtin_elementwise_fma(wv_, __builtin_shufflevector(v1, v1, 0, 1), acc2[4]);
                acc2[5]  = __builtin_elementwise_fma(wv_, __builtin_shufflevector(v1, v1, 2, 3), acc2[5]);
                acc2[6]  = __builtin_elementwise_fma(wv_, __builtin_shufflevector(v1, v1, 4, 5), acc2[6]);
                acc2[7]  = __builtin_elementwise_fma(wv_, __builtin_shufflevector(v1, v1, 6, 7), acc2[7]);
                acc2[8]  = __builtin_elementwise_fma(wv_, __builtin_shufflevector(v2, v2, 0, 1), acc2[8]);
                acc2[9]  = __builtin_elementwise_fma(wv_, __builtin_shufflevector(v2, v2, 2, 3), acc2[9]);
                acc2[10] = __builtin_elementwise_fma(wv_, __builtin_shufflevector(v2, v2, 4, 5), acc2[10]);
            }
        }
        float l[NCH];
        LOGITS_FROM_PK(l, acc2, ui0, ui1, ui2);
        float m = l[0];
#pragma unroll
        for (int c = 1; c < NCH; c++) m = fmaxf(m, l[c]);
        float s = 0.f;
#pragma unroll
        for (int c = 0; c < NCH; c++) { l[c] = __expf(l[c] - m); s += l[c]; }
        float is = 1.0f / s;

        if (FINAL) {
            float* qo = (float*)qout + (size_t)b * NCH * plane + (size_t)gy * WW + gx;
#pragma unroll
            for (int c = 0; c < NCH; c++) qo[c * plane] = l[c] * is;
        } else {
            half8* qo = (half8*)((f16*)qout + pixoff * CPAD);
            half8 o0, o1, o2;
#pragma unroll
            for (int k = 0; k < 8; k++) o0[k] = (f16)(l[k] * is);
#pragma unroll
            for (int k = 0; k < 8; k++) o1[k] = (f16)(l[8 + k] * is);
#pragma unroll
            for (int k = 0; k < 5; k++) o2[k] = (f16)(l[16 + k] * is);
            o2[5] = (f16)0.f; o2[6] = (f16)0.f; o2[7] = (f16)0.f;
            qo[0] = o0; qo[1] = o1; qo[2] = o2;
        }
    }
}

extern "C" void kernel_launch(void* const* d_in, const int* in_sizes, int n_in,
                              void* d_out, int out_size, void* d_ws, size_t ws_size,
                              hipStream_t stream) {
    const float* unary = (const float*)d_in[0];   // B,21,512,512
    const float* image = (const float*)d_in[1];   // B,3,512,512
    const float* edges = (const float*)d_in[2];   // B,512,512
    float* out = (float*)d_out;                   // B,21,512,512 fp32

    const size_t plane = (size_t)HH * WW;
    char* ws = (char*)d_ws;
    f16* wu = (f16*)ws;                                          // B*plane*48 f16 = 50.3 MB
    char* p1 = ws + sizeof(f16) * BATCH * plane * WUPAD;
    f16* qA = (f16*)p1;                                          // 25.2 MB
    f16* qB = qA + (size_t)BATCH * plane * CPAD;                 // 25.2 MB (total ~101 MB)

    dim3 gridW(WW / TXW, HH / TYW, BATCH);
    dim3 blockW(TXW, TYW, 1);
    setup_kernel<<<gridW, blockW, 0, stream>>>(image, edges, unary, wu, qA);

    const int nblk = (WW / TW) * (HH / TH) * BATCH;   // 1024
    f16* qa = qA;
    f16* qb = qB;
    const int npairs = NUM_ITERS / 2;                 // 5
    for (int it = 0; it < npairs - 1; it++) {
        crf_pair_kernel<false><<<nblk, NTHR, 0, stream>>>(qa, wu, (void*)qb);
        f16* t = qa; qa = qb; qb = t;
    }
    crf_pair_kernel<true><<<nblk, NTHR, 0, stream>>>(qa, wu, (void*)out);
}